// Round 1
// baseline (2590.148 us; speedup 1.0000x reference)
//
#include <hip/hip_runtime.h>
#include <math.h>

#define BN 4
#define SN 1024
#define EN 512
#define HN 8
#define LN 4
#define DN 64
#define OBSN 128
#define NR (BN*SN)            // 4096 rows
#define NB (NR*EN)            // elements per activation buffer
#define EPSF 1e-6f

__device__ __forceinline__ float logk_of(int h){
    const float start = -3.4657359027997265f;   // log(1/32)
    const float step  = -0.3960841031771117f;   // (log(1/512)-log(1/32))/7
    return logf(1.0f - expf(start + step*(float)h));
}
__device__ __forceinline__ float geluf(float x){
    float x3 = x*x*x;
    return 0.5f*x*(1.0f + tanhf(0.7978845608028654f*(x + 0.044715f*x3)));
}
__device__ __forceinline__ float siluf(float x){
    return x / (1.0f + expf(-x));
}

// ---------------- segment cumsum (inclusive) ----------------
__global__ void seg_kernel(const int* __restrict__ dones, int* __restrict__ seg){
    __shared__ int sm[SN];
    int b = blockIdx.x, t = threadIdx.x;
    sm[t] = dones[b*SN + t];
    __syncthreads();
    for (int off=1; off<SN; off<<=1){
        int v = (t>=off) ? sm[t-off] : 0;
        __syncthreads();
        sm[t] += v;
        __syncthreads();
    }
    seg[b*SN + t] = sm[t];
}

// ---------------- rmsnorm (one wave per row) ----------------
template<int COLS>
__global__ void rmsnorm_kernel(const float* __restrict__ A,
                               const float* __restrict__ scale,
                               float* __restrict__ O){
    constexpr int PER = COLS/64;
    int row  = blockIdx.x*4 + (threadIdx.x>>6);
    int lane = threadIdx.x & 63;
    const float* a = A + (size_t)row*COLS;
    float v[PER];
    float ss = 0.f;
    #pragma unroll
    for (int i=0;i<PER;i++){
        float x = a[lane + i*64];
        v[i] = x; ss += x*x;
    }
    #pragma unroll
    for (int off=32; off>0; off>>=1) ss += __shfl_xor(ss, off, 64);
    float rs = rsqrtf(ss*(1.0f/COLS) + EPSF);
    float* o = O + (size_t)row*COLS;
    #pragma unroll
    for (int i=0;i<PER;i++) o[lane + i*64] = v[i]*rs*scale[lane + i*64];
}

// ---------------- tiled f32 GEMM: C = epi(scale*(A@W) [+bias]) [+res] ----------------
// BM=64, BN=64, BK=16; 256 threads; 4x4 per thread.
template<int ACT, bool BIASF, bool RESF>
__global__ __launch_bounds__(256) void gemm_kernel(
    const float* __restrict__ A, const float* __restrict__ W,
    const float* __restrict__ bias, const float* __restrict__ res,
    float* __restrict__ C, int N, int K, int M, float scale)
{
    __shared__ float As[16][64];   // [k][row]
    __shared__ float Bs[16][64];   // [k][col]
    int t  = threadIdx.x;
    int ty = t>>4, tx = t&15;
    int row0 = blockIdx.y*64, col0 = blockIdx.x*64;
    float acc[4][4] = {};
    for (int k0=0; k0<K; k0+=16){
        {   // A tile: thread loads float4 along K
            int r = t>>2, kq = (t&3)*4;
            float4 a4 = *(const float4*)(A + (size_t)(row0+r)*K + k0 + kq);
            As[kq+0][r]=a4.x; As[kq+1][r]=a4.y; As[kq+2][r]=a4.z; As[kq+3][r]=a4.w;
        }
        {   // W tile: coalesced along M
            int kk = t>>4, cq = (t&15)*4;
            *(float4*)&Bs[kk][cq] = *(const float4*)(W + (size_t)(k0+kk)*M + col0 + cq);
        }
        __syncthreads();
        #pragma unroll
        for (int k=0;k<16;k++){
            float4 av = *(float4*)&As[k][ty*4];
            float4 bv = *(float4*)&Bs[k][tx*4];
            float a[4]={av.x,av.y,av.z,av.w}, b[4]={bv.x,bv.y,bv.z,bv.w};
            #pragma unroll
            for (int i=0;i<4;i++)
                #pragma unroll
                for (int j=0;j<4;j++)
                    acc[i][j] += a[i]*b[j];
        }
        __syncthreads();
    }
    #pragma unroll
    for (int i=0;i<4;i++){
        int row = row0 + ty*4 + i;
        int col = col0 + tx*4;
        float o[4];
        #pragma unroll
        for (int j=0;j<4;j++){
            float x = acc[i][j]*scale;
            if (BIASF) x += bias[col+j];
            if (ACT==1) x = siluf(x);
            if (ACT==2) x = geluf(x);
            if (RESF) x += res[(size_t)row*M + col + j];
            o[j] = x;
        }
        *(float4*)(C + (size_t)row*M + col) = make_float4(o[0],o[1],o[2],o[3]);
    }
}

// ---------------- elementwise multiply ----------------
__global__ void mul_kernel(const float* __restrict__ A, const float* __restrict__ Bv,
                           float* __restrict__ O){
    int i = blockIdx.x*blockDim.x + threadIdx.x;
    float4 a = ((const float4*)A)[i];
    float4 b = ((const float4*)Bv)[i];
    ((float4*)O)[i] = make_float4(a.x*b.x, a.y*b.y, a.z*b.z, a.w*b.w);
}

// ---------------- retention core: ret = inner + cross, then groupnorm -> Y ----------------
// grid: (SN/16, BN*HN); block 256. thread (r=t>>4, c=t&15): row n0+r, cols c*4..c*4+3
__global__ __launch_bounds__(256) void retention_kernel(
    const float* __restrict__ Q, const float* __restrict__ Kb, const float* __restrict__ Vb,
    const float* __restrict__ hstate, const int* __restrict__ tsid, const int* __restrict__ seg,
    const float* __restrict__ gns, const float* __restrict__ gnb,
    float* __restrict__ Y, int layer)
{
    int bh = blockIdx.y; int b = bh>>3; int h = bh&7;
    int n0 = blockIdx.x*16;
    int t = threadIdx.x; int r = t>>4; int c = t&15;
    __shared__ float q_s[16][68];
    __shared__ float k_s[16][68];
    __shared__ float v_s[16][68];
    __shared__ float h_s[64][68];
    __shared__ float s_s[16][16];
    __shared__ float tsn_s[16]; __shared__ int segn_s[16];
    __shared__ float tsm_s[16]; __shared__ int segm_s[16];
    float lk = logk_of(h);

    *(float4*)&q_s[r][c*4] = *(const float4*)(Q + (size_t)(b*SN + n0 + r)*EN + h*64 + c*4);
    const float* h0 = hstate + ((size_t)bh*LN + layer)*4096;
    #pragma unroll
    for (int i=0;i<4;i++){
        int f = t + i*256; int d = f>>4; int e4 = (f&15)*4;
        *(float4*)&h_s[d][e4] = *(const float4*)(h0 + d*64 + e4);
    }
    if (t<16){ tsn_s[t] = (float)tsid[b*SN+n0+t]; segn_s[t] = seg[b*SN+n0+t]; }
    __syncthreads();

    float acc[4] = {0.f,0.f,0.f,0.f};
    {   // cross term: xi[n] * (q[n] . h0[:,e])
        float xin = (segn_s[r]==0) ? expf((tsn_s[r]+1.0f)*lk) : 0.0f;
        if (xin != 0.0f){
            float t0=0,t1=0,t2=0,t3=0;
            #pragma unroll
            for (int d=0; d<64; d++){
                float qd = q_s[r][d];
                float4 hv = *(float4*)&h_s[d][c*4];
                t0 += qd*hv.x; t1 += qd*hv.y; t2 += qd*hv.z; t3 += qd*hv.w;
            }
            acc[0]=xin*t0; acc[1]=xin*t1; acc[2]=xin*t2; acc[3]=xin*t3;
        }
    }

    // masked decay attention over m-tiles 0..blockIdx.x (timestep-causal)
    for (int mt=0; mt<=blockIdx.x; ++mt){
        int m0 = mt*16;
        size_t rowM = (size_t)(b*SN + m0 + r)*EN + h*64;
        *(float4*)&k_s[r][c*4] = *(const float4*)(Kb + rowM + c*4);
        *(float4*)&v_s[r][c*4] = *(const float4*)(Vb + rowM + c*4);
        if (t<16){ tsm_s[t] = (float)tsid[b*SN+m0+t]; segm_s[t] = seg[b*SN+m0+t]; }
        __syncthreads();
        float dot = 0.f;
        #pragma unroll
        for (int d=0; d<64; d++) dot += q_s[r][d]*k_s[c][d];
        float dtv = tsn_s[r] - tsm_s[c];
        float sv = 0.f;
        if (dtv >= 0.f && segn_s[r]==segm_s[c]) sv = dot*expf(dtv*lk);
        s_s[r][c] = sv;
        __syncthreads();
        #pragma unroll
        for (int mm=0; mm<16; mm++){
            float s = s_s[r][mm];
            float4 vv = *(float4*)&v_s[mm][c*4];
            acc[0]+=s*vv.x; acc[1]+=s*vv.y; acc[2]+=s*vv.z; acc[3]+=s*vv.w;
        }
        __syncthreads();
    }

    // groupnorm over D=64 (16 lanes x 4 vals), two-pass for stability
    float sum = acc[0]+acc[1]+acc[2]+acc[3];
    #pragma unroll
    for (int off=1; off<16; off<<=1) sum += __shfl_xor(sum, off, 16);
    float mu = sum*(1.0f/64.0f);
    float d0=acc[0]-mu, d1=acc[1]-mu, d2=acc[2]-mu, d3=acc[3]-mu;
    float ssq = d0*d0+d1*d1+d2*d2+d3*d3;
    #pragma unroll
    for (int off=1; off<16; off<<=1) ssq += __shfl_xor(ssq, off, 16);
    float rs = rsqrtf(ssq*(1.0f/64.0f) + EPSF);
    int e = h*64 + c*4;
    float4 o;
    o.x = d0*rs*gns[e+0] + gnb[e+0];
    o.y = d1*rs*gns[e+1] + gnb[e+1];
    o.z = d2*rs*gns[e+2] + gnb[e+2];
    o.w = d3*rs*gns[e+3] + gnb[e+3];
    *(float4*)(Y + (size_t)(b*SN + n0 + r)*EN + e) = o;
}

// ---------------- h_new: h0*h_decay + sum_m eta[m] k[m,d] v[m,e] ----------------
// grid BN*HN, block 256; thread: d=t>>2, e0=(t&3)*16 (16 accumulators)
__global__ __launch_bounds__(256) void hnew_kernel(
    const float* __restrict__ Kb, const float* __restrict__ Vb,
    const float* __restrict__ hstate, const int* __restrict__ tsid, const int* __restrict__ seg,
    float* __restrict__ Hout, int layer)
{
    int bh = blockIdx.x; int b = bh>>3; int h = bh&7;
    int t = threadIdx.x;
    int r = t>>4, c = t&15;
    int d = t>>2, e0 = (t&3)*16;
    __shared__ float k_s[16][68], v_s[16][68];
    __shared__ float eta_s[16];
    float lk = logk_of(h);
    float tmax = (float)tsid[b*SN + SN-1];
    int segl = seg[b*SN + SN-1];
    float acc[16] = {};
    for (int mt=0; mt<SN/16; ++mt){
        int m0 = mt*16;
        size_t rowM = (size_t)(b*SN + m0 + r)*EN + h*64;
        *(float4*)&k_s[r][c*4] = *(const float4*)(Kb + rowM + c*4);
        *(float4*)&v_s[r][c*4] = *(const float4*)(Vb + rowM + c*4);
        if (t<16){
            float tsm = (float)tsid[b*SN+m0+t];
            eta_s[t] = (seg[b*SN+m0+t]==segl) ? expf((tmax - tsm)*lk) : 0.f;
        }
        __syncthreads();
        #pragma unroll
        for (int mm=0; mm<16; mm++){
            float ek = eta_s[mm]*k_s[mm][d];
            #pragma unroll
            for (int u=0; u<4; u++){
                float4 vv = *(float4*)&v_s[mm][e0+u*4];
                acc[u*4+0]+=ek*vv.x; acc[u*4+1]+=ek*vv.y;
                acc[u*4+2]+=ek*vv.z; acc[u*4+3]+=ek*vv.w;
            }
        }
        __syncthreads();
    }
    float hd = (segl==0) ? expf((tmax+1.0f)*lk) : 0.f;
    const float* h0 = hstate + ((size_t)bh*LN + layer)*4096;
    float* ho = Hout + ((size_t)bh*LN + layer)*4096;
    #pragma unroll
    for (int u=0; u<4; u++){
        float4 hv = *(const float4*)(h0 + d*64 + e0 + u*4);
        float4 o;
        o.x = hv.x*hd + acc[u*4+0];
        o.y = hv.y*hd + acc[u*4+1];
        o.z = hv.z*hd + acc[u*4+2];
        o.w = hv.w*hd + acc[u*4+3];
        *(float4*)(ho + d*64 + e0 + u*4) = o;
    }
}

// ---------------- v_loc = ZN @ w2 + b2 (M=1) ----------------
__global__ void vloc_kernel(const float* __restrict__ ZN, const float* __restrict__ w2,
                            const float* __restrict__ b2, float* __restrict__ out){
    int row  = blockIdx.x*4 + (threadIdx.x>>6);
    int lane = threadIdx.x & 63;
    const float* z = ZN + (size_t)row*EN;
    float s = 0.f;
    #pragma unroll
    for (int i=0;i<8;i++) s += z[lane + i*64]*w2[lane + i*64];
    #pragma unroll
    for (int off=32; off>0; off>>=1) s += __shfl_xor(s, off, 64);
    if (lane==0) out[row] = s + b2[0];
}

// ---------------- host ----------------
static inline void launch_gemm(const float* A, const float* W, const float* bias,
                               const float* res, float* C, int N, int K, int M,
                               float scale, int act, hipStream_t s){
    dim3 g(M/64, N/64), b(256,1,1);
    if (bias)           gemm_kernel<2,true ,false><<<g,b,0,s>>>(A,W,bias,res,C,N,K,M,scale);
    else if (res)       gemm_kernel<0,false,true ><<<g,b,0,s>>>(A,W,bias,res,C,N,K,M,scale);
    else if (act==1)    gemm_kernel<1,false,false><<<g,b,0,s>>>(A,W,bias,res,C,N,K,M,scale);
    else if (act==2)    gemm_kernel<2,false,false><<<g,b,0,s>>>(A,W,bias,res,C,N,K,M,scale);
    else                gemm_kernel<0,false,false><<<g,b,0,s>>>(A,W,bias,res,C,N,K,M,scale);
}

extern "C" void kernel_launch(void* const* d_in, const int* in_sizes, int n_in,
                              void* d_out, int out_size, void* d_ws, size_t ws_size,
                              hipStream_t stream){
    const float* obs       = (const float*)d_in[0];
    const float* hstate    = (const float*)d_in[1];
    const int*   dones     = (const int*)  d_in[2];
    const int*   tsid      = (const int*)  d_in[3];
    const float* ln_enc    = (const float*)d_in[4];
    const float* w_enc     = (const float*)d_in[5];
    const float* ln_shared = (const float*)d_in[6];
    const float* wq        = (const float*)d_in[7];
    const float* wk        = (const float*)d_in[8];
    const float* wv        = (const float*)d_in[9];
    const float* wg        = (const float*)d_in[10];
    const float* wo        = (const float*)d_in[11];
    const float* gns       = (const float*)d_in[12];
    const float* gnb       = (const float*)d_in[13];
    const float* ln1       = (const float*)d_in[14];
    const float* ln2       = (const float*)d_in[15];
    const float* swg       = (const float*)d_in[16];
    const float* swl       = (const float*)d_in[17];
    const float* swo       = (const float*)d_in[18];
    const float* hw1       = (const float*)d_in[19];
    const float* hb1       = (const float*)d_in[20];
    const float* hln       = (const float*)d_in[21];
    const float* hw2       = (const float*)d_in[22];
    const float* hb2       = (const float*)d_in[23];

    float* out_v = (float*)d_out;                 // (B,S,1)
    float* out_x = out_v + NR;                    // (B,S,E)
    float* out_h = out_x + (size_t)NR*EN;         // (B,H,L,D,D)

    float* ws  = (float*)d_ws;
    float* XIN = ws + 0*(size_t)NB;
    float* Qb  = ws + 1*(size_t)NB;
    float* Kb  = ws + 2*(size_t)NB;
    float* Vb  = ws + 3*(size_t)NB;
    float* Gb  = ws + 4*(size_t)NB;
    float* Yb  = ws + 5*(size_t)NB;
    int*   seg = (int*)(ws + 6*(size_t)NB);

    seg_kernel<<<BN, SN, 0, stream>>>(dones, seg);

    // encoder: x = gelu(rmsnorm(obs) @ w_enc)   (XIN holds (NR,128) temp)
    rmsnorm_kernel<OBSN><<<NR/4, 256, 0, stream>>>(obs, ln_enc, XIN);
    launch_gemm(XIN, w_enc, nullptr, nullptr, out_x, NR, OBSN, EN, 1.f, 2, stream);

    const size_t WE = (size_t)EN*EN;
    for (int l=0; l<LN; ++l){
        rmsnorm_kernel<EN><<<NR/4, 256, 0, stream>>>(out_x, ln_shared, XIN);
        launch_gemm(XIN, wq + l*WE, nullptr, nullptr, Qb, NR, EN, EN, 1.f,    0, stream);
        launch_gemm(XIN, wk + l*WE, nullptr, nullptr, Kb, NR, EN, EN, 0.125f, 0, stream);
        launch_gemm(XIN, wv + l*WE, nullptr, nullptr, Vb, NR, EN, EN, 1.f,    0, stream);
        launch_gemm(XIN, wg + l*WE, nullptr, nullptr, Gb, NR, EN, EN, 1.f,    1, stream);
        retention_kernel<<<dim3(SN/16, BN*HN), 256, 0, stream>>>(
            Qb, Kb, Vb, hstate, tsid, seg, gns + l*EN, gnb + l*EN, Yb, l);
        hnew_kernel<<<BN*HN, 256, 0, stream>>>(Kb, Vb, hstate, tsid, seg, out_h, l);
        mul_kernel<<<NB/1024, 256, 0, stream>>>(Gb, Yb, Gb);                 // G = silu(g)*y
        launch_gemm(Gb, wo + l*WE, nullptr, XIN, Qb, NR, EN, EN, 1.f, 0, stream); // Qb = G@wo + xin
        rmsnorm_kernel<EN><<<NR/4, 256, 0, stream>>>(Qb, ln1 + l*EN, Kb);    // x1 = Kb
        launch_gemm(Kb, swg + l*WE, nullptr, nullptr, Vb, NR, EN, EN, 1.f, 1, stream); // silu gate
        launch_gemm(Kb, swl + l*WE, nullptr, nullptr, Gb, NR, EN, EN, 1.f, 0, stream); // lin
        mul_kernel<<<NB/1024, 256, 0, stream>>>(Vb, Gb, Vb);                 // t
        launch_gemm(Vb, swo + l*WE, nullptr, Kb, Qb, NR, EN, EN, 1.f, 0, stream);  // Qb = t@swo + x1
        rmsnorm_kernel<EN><<<NR/4, 256, 0, stream>>>(Qb, ln2 + l*EN, out_x); // x
    }

    // head
    launch_gemm(out_x, hw1, hb1, nullptr, Yb, NR, EN, EN, 1.f, 2, stream);   // z = gelu(x@w1+b1)
    rmsnorm_kernel<EN><<<NR/4, 256, 0, stream>>>(Yb, hln, XIN);              // zn
    vloc_kernel<<<NR/4, 256, 0, stream>>>(XIN, hw2, hb2, out_v);
}

// Round 2
// 1468.111 us; speedup vs baseline: 1.7643x; 1.7643x over previous
//
#include <hip/hip_runtime.h>
#include <math.h>

#define BN 4
#define SN 1024
#define EN 512
#define HN 8
#define LN 4
#define DN 64
#define OBSN 128
#define NR (BN*SN)            // 4096 rows
#define NB (NR*EN)            // elements per activation buffer
#define EPSF 1e-6f

typedef __attribute__((ext_vector_type(8))) short short8v;
typedef __attribute__((ext_vector_type(4))) float f32x4;

__device__ __forceinline__ float logk_of(int h){
    const float start = -3.4657359027997265f;   // log(1/32)
    const float step  = -0.3960841031771117f;   // (log(1/512)-log(1/32))/7
    return logf(1.0f - expf(start + step*(float)h));
}
__device__ __forceinline__ float geluf(float x){
    float x3 = x*x*x;
    return 0.5f*x*(1.0f + tanhf(0.7978845608028654f*(x + 0.044715f*x3)));
}
__device__ __forceinline__ float siluf(float x){
    return x / (1.0f + expf(-x));
}
__device__ __forceinline__ unsigned short f2bf(float x){
    union { float f; unsigned u; } v; v.f = x;
    unsigned r = v.u + 0x7FFFu + ((v.u >> 16) & 1u);
    return (unsigned short)(r >> 16);
}
__device__ __forceinline__ void load_lds16(const void* g, void* l){
    __builtin_amdgcn_global_load_lds((const __attribute__((address_space(1))) void*)g,
                                     (__attribute__((address_space(3))) void*)l, 16, 0, 0);
}

// ---------------- segment cumsum (inclusive) ----------------
__global__ void seg_kernel(const int* __restrict__ dones, int* __restrict__ seg){
    __shared__ int sm[SN];
    int b = blockIdx.x, t = threadIdx.x;
    sm[t] = dones[b*SN + t];
    __syncthreads();
    for (int off=1; off<SN; off<<=1){
        int v = (t>=off) ? sm[t-off] : 0;
        __syncthreads();
        sm[t] += v;
        __syncthreads();
    }
    seg[b*SN + t] = sm[t];
}

// ---------------- weight convert+transpose: f32 [K][M] -> bf16 [M][K] ----------------
__global__ void wconv_kernel(const float* __restrict__ src, unsigned short* __restrict__ dst,
                             int K, int M){
    __shared__ unsigned short tile[32][33];
    int mat = blockIdx.z;
    const float* s = src + (size_t)mat*K*M;
    unsigned short* d = dst + (size_t)mat*K*M;
    int k0 = blockIdx.y*32, m0 = blockIdx.x*32;
    int tx = threadIdx.x, ty = threadIdx.y;   // 32, 8
    #pragma unroll
    for (int i=0;i<32;i+=8)
        tile[tx][ty+i] = f2bf(s[(size_t)(k0+ty+i)*M + m0+tx]);
    __syncthreads();
    #pragma unroll
    for (int i=0;i<32;i+=8)
        d[(size_t)(m0+ty+i)*K + k0+tx] = tile[ty+i][tx];
}

// ---------------- rmsnorm (one wave per row), optional f32 + bf16 outputs ----------------
template<int COLS, bool WF32, bool WBF>
__global__ void rmsnorm_kernel(const float* __restrict__ A,
                               const float* __restrict__ scale,
                               float* __restrict__ Of,
                               unsigned short* __restrict__ Ob){
    constexpr int PER = COLS/64;
    int row  = blockIdx.x*4 + (threadIdx.x>>6);
    int lane = threadIdx.x & 63;
    const float* a = A + (size_t)row*COLS;
    float v[PER];
    float ss = 0.f;
    #pragma unroll
    for (int i=0;i<PER;i++){
        float x = a[lane + i*64];
        v[i] = x; ss += x*x;
    }
    #pragma unroll
    for (int off=32; off>0; off>>=1) ss += __shfl_xor(ss, off, 64);
    float rs = rsqrtf(ss*(1.0f/COLS) + EPSF);
    #pragma unroll
    for (int i=0;i<PER;i++){
        float o = v[i]*rs*scale[lane + i*64];
        if (WF32) Of[(size_t)row*COLS + lane + i*64] = o;
        if (WBF)  Ob[(size_t)row*COLS + lane + i*64] = f2bf(o);
    }
}

// ---------------- bf16 MFMA GEMM: C = epi(scale*(A@Wt^T) [+bias]) [+res] ----------------
// A bf16 [NR][K], Wt bf16 [512][K] (pre-transposed weights). BM=BN=64, BK=64.
// 256 threads = 4 waves (2x2); wave = 32x32 out = 2x2 16x16 frags.
template<int ACT, bool BIASF, bool RESF>
__global__ __launch_bounds__(256) void gemm_bf16(
    const unsigned short* __restrict__ A,
    const unsigned short* __restrict__ Wt,
    const float* __restrict__ bias, const float* __restrict__ res,
    float* __restrict__ C, int K, float scale)
{
    __shared__ unsigned short As[64*64 + 64*64];
    unsigned short* Bs = As + 64*64;
    int t = threadIdx.x;
    int row0 = blockIdx.y*64, col0 = blockIdx.x*64;
    int w = t>>6, lane = t&63;
    int wr = w>>1, wc = w&1;
    f32x4 acc[2][2];
    #pragma unroll
    for (int m=0;m<2;m++)
        #pragma unroll
        for (int n=0;n<2;n++){ acc[m][n][0]=0.f; acc[m][n][1]=0.f; acc[m][n][2]=0.f; acc[m][n][3]=0.f; }

    for (int k0=0; k0<K; k0+=64){
        #pragma unroll
        for (int i=0;i<2;i++){   // A tile 8192 B
            int o = i*4096 + t*16;
            int arow = o>>7, acolb = o&127;
            load_lds16(A + (size_t)(row0+arow)*K + k0 + (acolb>>1), (char*)As + o);
        }
        #pragma unroll
        for (int i=0;i<2;i++){   // B tile 8192 B
            int o = i*4096 + t*16;
            int brow = o>>7, bcolb = o&127;
            load_lds16(Wt + (size_t)(col0+brow)*K + k0 + (bcolb>>1), (char*)Bs + o);
        }
        __syncthreads();
        #pragma unroll
        for (int kk=0; kk<64; kk+=32){
            int kb = kk + (lane>>4)*8;   // element offset in k
            short8v a[2], b[2];
            #pragma unroll
            for (int m=0;m<2;m++){
                int arow = wr*32 + m*16 + (lane&15);
                a[m] = *(const short8v*)((const char*)As + arow*128 + kb*2);
            }
            #pragma unroll
            for (int n=0;n<2;n++){
                int bcol = wc*32 + n*16 + (lane&15);
                b[n] = *(const short8v*)((const char*)Bs + bcol*128 + kb*2);
            }
            #pragma unroll
            for (int m=0;m<2;m++)
                #pragma unroll
                for (int n=0;n<2;n++)
                    acc[m][n] = __builtin_amdgcn_mfma_f32_16x16x32_bf16(a[m], b[n], acc[m][n], 0,0,0);
        }
        __syncthreads();
    }
    #pragma unroll
    for (int m=0;m<2;m++){
        #pragma unroll
        for (int n=0;n<2;n++){
            int col = col0 + wc*32 + n*16 + (lane&15);
            #pragma unroll
            for (int j=0;j<4;j++){
                int row = row0 + wr*32 + m*16 + (lane>>4)*4 + j;
                float x = acc[m][n][j]*scale;
                if (BIASF) x += bias[col];
                if (ACT==1) x = siluf(x);
                if (ACT==2) x = geluf(x);
                if (RESF) x += res[(size_t)row*512 + col];
                C[(size_t)row*512 + col] = x;
            }
        }
    }
}

// ---------------- elementwise multiply -> bf16 ----------------
__global__ void mulb_kernel(const float* __restrict__ A, const float* __restrict__ Bv,
                            unsigned short* __restrict__ O){
    int i = blockIdx.x*blockDim.x + threadIdx.x;
    float4 a = ((const float4*)A)[i];
    float4 b = ((const float4*)Bv)[i];
    ushort4 o;
    o.x = f2bf(a.x*b.x); o.y = f2bf(a.y*b.y);
    o.z = f2bf(a.z*b.z); o.w = f2bf(a.w*b.w);
    ((ushort4*)O)[i] = o;
}

// ---------------- retention core: ret = inner + cross, then groupnorm -> Y ----------------
// grid: (SN/16, BN*HN) with tile order reversed; block 256.
// thread (r=t>>4, c=t&15): row n0+r, out cols c*4..c*4+3; m-tiles 32 wide.
__global__ __launch_bounds__(256) void retention_kernel(
    const float* __restrict__ Q, const float* __restrict__ Kb, const float* __restrict__ Vb,
    const float* __restrict__ hstate, const int* __restrict__ tsid, const int* __restrict__ seg,
    const float* __restrict__ gns, const float* __restrict__ gnb,
    float* __restrict__ Y, int layer)
{
    int bh = blockIdx.y; int b = bh>>3; int h = bh&7;
    int tile = (int)gridDim.x - 1 - (int)blockIdx.x;   // heavy blocks first
    int n0 = tile*16;
    int t = threadIdx.x; int r = t>>4; int c = t&15;
    __shared__ float smem[64][68];     // phase 1: hstate[64][64]; phase 2: K rows 0..31, V rows 32..63
    __shared__ float q_s[16][68];
    __shared__ float s_s[16][32];
    __shared__ float tsn_s[16]; __shared__ int segn_s[16];
    __shared__ float tsm_s[32]; __shared__ int segm_s[32];
    float lk = logk_of(h);

    *(float4*)&q_s[r][c*4] = *(const float4*)(Q + (size_t)(b*SN + n0 + r)*EN + h*64 + c*4);
    const float* h0 = hstate + ((size_t)bh*LN + layer)*4096;
    #pragma unroll
    for (int i=0;i<4;i++){
        int f = t + i*256; int d = f>>4; int e4 = (f&15)*4;
        *(float4*)&smem[d][e4] = *(const float4*)(h0 + d*64 + e4);
    }
    if (t<16){ tsn_s[t] = (float)tsid[b*SN+n0+t]; segn_s[t] = seg[b*SN+n0+t]; }
    __syncthreads();

    float acc[4] = {0.f,0.f,0.f,0.f};
    {   // cross term: xi[n] * (q[n] . h0[:,e])
        float xin = (segn_s[r]==0) ? expf((tsn_s[r]+1.0f)*lk) : 0.0f;
        if (xin != 0.0f){
            float t0=0,t1=0,t2=0,t3=0;
            #pragma unroll
            for (int d=0; d<64; d++){
                float qd = q_s[r][d];
                float4 hv = *(float4*)&smem[d][c*4];
                t0 += qd*hv.x; t1 += qd*hv.y; t2 += qd*hv.z; t3 += qd*hv.w;
            }
            acc[0]=xin*t0; acc[1]=xin*t1; acc[2]=xin*t2; acc[3]=xin*t3;
        }
    }

    // masked decay attention over 32-wide m-tiles (timestep-causal)
    int mt_max = (n0+15)>>5;
    for (int mt=0; mt<=mt_max; ++mt){
        __syncthreads();   // smem free of previous readers
        int m0 = mt*32;
        #pragma unroll
        for (int i=0;i<2;i++){
            int f = t + i*256;         // 0..511
            int row = f>>4, c4 = (f&15)*4;
            size_t g = (size_t)(b*SN + m0 + row)*EN + h*64 + c4;
            *(float4*)&smem[row][c4]    = *(const float4*)(Kb + g);
            *(float4*)&smem[32+row][c4] = *(const float4*)(Vb + g);
        }
        if (t<32){ tsm_s[t] = (float)tsid[b*SN+m0+t]; segm_s[t] = seg[b*SN+m0+t]; }
        __syncthreads();
        float d0=0.f, d1=0.f;
        #pragma unroll
        for (int d=0; d<64; d++){
            float qv = q_s[r][d];
            d0 += qv * smem[c][d];
            d1 += qv * smem[c+16][d];
        }
        float dt0 = tsn_s[r]-tsm_s[c];
        float dt1 = tsn_s[r]-tsm_s[c+16];
        s_s[r][c]    = (dt0>=0.f && segn_s[r]==segm_s[c])    ? d0*expf(dt0*lk) : 0.f;
        s_s[r][c+16] = (dt1>=0.f && segn_s[r]==segm_s[c+16]) ? d1*expf(dt1*lk) : 0.f;
        __syncthreads();
        #pragma unroll
        for (int mm=0; mm<32; mm++){
            float s = s_s[r][mm];
            float4 vv = *(float4*)&smem[32+mm][c*4];
            acc[0]+=s*vv.x; acc[1]+=s*vv.y; acc[2]+=s*vv.z; acc[3]+=s*vv.w;
        }
    }

    // groupnorm over D=64 (16 lanes x 4 vals)
    float sum = acc[0]+acc[1]+acc[2]+acc[3];
    #pragma unroll
    for (int off=1; off<16; off<<=1) sum += __shfl_xor(sum, off, 16);
    float mu = sum*(1.0f/64.0f);
    float d0=acc[0]-mu, d1=acc[1]-mu, d2=acc[2]-mu, d3=acc[3]-mu;
    float ssq = d0*d0+d1*d1+d2*d2+d3*d3;
    #pragma unroll
    for (int off=1; off<16; off<<=1) ssq += __shfl_xor(ssq, off, 16);
    float rs = rsqrtf(ssq*(1.0f/64.0f) + EPSF);
    int e = h*64 + c*4;
    float4 o;
    o.x = d0*rs*gns[e+0] + gnb[e+0];
    o.y = d1*rs*gns[e+1] + gnb[e+1];
    o.z = d2*rs*gns[e+2] + gnb[e+2];
    o.w = d3*rs*gns[e+3] + gnb[e+3];
    *(float4*)(Y + (size_t)(b*SN + n0 + r)*EN + e) = o;
}

// ---------------- h_new partial: sum over 8 m-tiles of eta*k x v ----------------
// grid (BN*HN, 8); block 256; thread: d=t>>2, e0=(t&3)*16
__global__ __launch_bounds__(256) void hnew_partial(
    const float* __restrict__ Kb, const float* __restrict__ Vb,
    const int* __restrict__ tsid, const int* __restrict__ seg,
    float* __restrict__ part)
{
    int bh = blockIdx.x; int b = bh>>3; int h = bh&7;
    int ch = blockIdx.y;
    int t = threadIdx.x;
    int r = t>>4, c = t&15;
    int d = t>>2, e0 = (t&3)*16;
    __shared__ float k_s[16][68], v_s[16][68];
    __shared__ float eta_s[16];
    float lk = logk_of(h);
    float tmax = (float)tsid[b*SN + SN-1];
    int segl = seg[b*SN + SN-1];
    float acc[16] = {};
    for (int mt=ch*8; mt<ch*8+8; ++mt){
        int m0 = mt*16;
        size_t rowM = (size_t)(b*SN + m0 + r)*EN + h*64;
        *(float4*)&k_s[r][c*4] = *(const float4*)(Kb + rowM + c*4);
        *(float4*)&v_s[r][c*4] = *(const float4*)(Vb + rowM + c*4);
        if (t<16){
            float tsm = (float)tsid[b*SN+m0+t];
            eta_s[t] = (seg[b*SN+m0+t]==segl) ? expf((tmax - tsm)*lk) : 0.f;
        }
        __syncthreads();
        #pragma unroll
        for (int mm=0; mm<16; mm++){
            float ek = eta_s[mm]*k_s[mm][d];
            #pragma unroll
            for (int u=0; u<4; u++){
                float4 vv = *(float4*)&v_s[mm][e0+u*4];
                acc[u*4+0]+=ek*vv.x; acc[u*4+1]+=ek*vv.y;
                acc[u*4+2]+=ek*vv.z; acc[u*4+3]+=ek*vv.w;
            }
        }
        __syncthreads();
    }
    float* po = part + ((size_t)bh*8 + ch)*4096;
    #pragma unroll
    for (int u=0; u<4; u++)
        *(float4*)(po + d*64 + e0 + u*4) = make_float4(acc[u*4+0],acc[u*4+1],acc[u*4+2],acc[u*4+3]);
}

// ---------------- h_new reduce: out = h0*decay + sum parts ----------------
__global__ void hreduce_kernel(const float* __restrict__ part, const float* __restrict__ hstate,
                               const int* __restrict__ tsid, const int* __restrict__ seg,
                               float* __restrict__ Hout, int layer){
    int bh = blockIdx.x; int b = bh>>3; int h = bh&7;
    int t = threadIdx.x;
    float lk = logk_of(h);
    float tmax = (float)tsid[b*SN + SN-1];
    int segl = seg[b*SN + SN-1];
    float hd = (segl==0) ? expf((tmax+1.0f)*lk) : 0.f;
    const float* h0 = hstate + ((size_t)bh*LN + layer)*4096;
    float* ho = Hout + ((size_t)bh*LN + layer)*4096;
    int e = t*4;
    float4 s = *(const float4*)(h0 + e);
    float4 o = make_float4(s.x*hd, s.y*hd, s.z*hd, s.w*hd);
    #pragma unroll
    for (int ch=0; ch<8; ch++){
        float4 p = *(const float4*)(part + ((size_t)bh*8 + ch)*4096 + e);
        o.x+=p.x; o.y+=p.y; o.z+=p.z; o.w+=p.w;
    }
    *(float4*)(ho + e) = o;
}

// ---------------- v_loc = ZN @ w2 + b2 (M=1) ----------------
__global__ void vloc_kernel(const float* __restrict__ ZN, const float* __restrict__ w2,
                            const float* __restrict__ b2, float* __restrict__ out){
    int row  = blockIdx.x*4 + (threadIdx.x>>6);
    int lane = threadIdx.x & 63;
    const float* z = ZN + (size_t)row*EN;
    float s = 0.f;
    #pragma unroll
    for (int i=0;i<8;i++) s += z[lane + i*64]*w2[lane + i*64];
    #pragma unroll
    for (int off=32; off>0; off>>=1) s += __shfl_xor(s, off, 64);
    if (lane==0) out[row] = s + b2[0];
}

// ---------------- host ----------------
static inline void launch_gemm(const unsigned short* A, const unsigned short* Wt,
                               const float* bias, const float* res, float* C,
                               int K, float scale, int act, hipStream_t s){
    dim3 g(8, 64), b(256,1,1);
    if (bias)           gemm_bf16<2,true ,false><<<g,b,0,s>>>(A,Wt,bias,res,C,K,scale);
    else if (res)       gemm_bf16<0,false,true ><<<g,b,0,s>>>(A,Wt,bias,res,C,K,scale);
    else if (act==1)    gemm_bf16<1,false,false><<<g,b,0,s>>>(A,Wt,bias,res,C,K,scale);
    else if (act==2)    gemm_bf16<2,false,false><<<g,b,0,s>>>(A,Wt,bias,res,C,K,scale);
    else                gemm_bf16<0,false,false><<<g,b,0,s>>>(A,Wt,bias,res,C,K,scale);
}

extern "C" void kernel_launch(void* const* d_in, const int* in_sizes, int n_in,
                              void* d_out, int out_size, void* d_ws, size_t ws_size,
                              hipStream_t stream){
    const float* obs       = (const float*)d_in[0];
    const float* hstate    = (const float*)d_in[1];
    const int*   dones     = (const int*)  d_in[2];
    const int*   tsid      = (const int*)  d_in[3];
    const float* ln_enc    = (const float*)d_in[4];
    const float* w_enc     = (const float*)d_in[5];
    const float* ln_shared = (const float*)d_in[6];
    const float* wq        = (const float*)d_in[7];
    const float* wk        = (const float*)d_in[8];
    const float* wv        = (const float*)d_in[9];
    const float* wg        = (const float*)d_in[10];
    const float* wo        = (const float*)d_in[11];
    const float* gns       = (const float*)d_in[12];
    const float* gnb       = (const float*)d_in[13];
    const float* ln1       = (const float*)d_in[14];
    const float* ln2       = (const float*)d_in[15];
    const float* swg       = (const float*)d_in[16];
    const float* swl       = (const float*)d_in[17];
    const float* swo       = (const float*)d_in[18];
    const float* hw1       = (const float*)d_in[19];
    const float* hb1       = (const float*)d_in[20];
    const float* hln       = (const float*)d_in[21];
    const float* hw2       = (const float*)d_in[22];
    const float* hb2       = (const float*)d_in[23];

    float* out_v = (float*)d_out;                 // (B,S,1)
    float* out_x = out_v + NR;                    // (B,S,E)
    float* out_h = out_x + (size_t)NR*EN;         // (B,H,L,D,D)

    float* ws    = (float*)d_ws;
    float* XIN   = ws + 0*(size_t)NB;
    float* Qb    = ws + 1*(size_t)NB;
    float* Kb    = ws + 2*(size_t)NB;
    float* Vb    = ws + 3*(size_t)NB;
    float* Gb    = ws + 4*(size_t)NB;
    float* Yb    = ws + 5*(size_t)NB;
    float* hpart = ws + 6*(size_t)NB;             // 32*8*4096 f32
    int*   seg   = (int*)(hpart + 32*8*4096);
    unsigned short* wtb  = (unsigned short*)(seg + NR);
    const size_t WEm = (size_t)EN*EN;             // 262144
    unsigned short* wqT   = wtb;
    unsigned short* wkT   = wqT + 4*WEm;
    unsigned short* wvT   = wkT + 4*WEm;
    unsigned short* wgT   = wvT + 4*WEm;
    unsigned short* woT   = wgT + 4*WEm;
    unsigned short* sgT   = woT + 4*WEm;
    unsigned short* slT   = sgT + 4*WEm;
    unsigned short* soT   = slT + 4*WEm;
    unsigned short* wencT = soT + 4*WEm;          // 512x128
    unsigned short* w1T   = wencT + (size_t)EN*OBSN;
    unsigned short* S1b   = w1T + WEm;            // activation bf16 slot 1 (NB)
    unsigned short* S2b   = S1b + (size_t)NB;     // activation bf16 slot 2 (NB)
    unsigned short* encb  = S2b + (size_t)NB;     // 4096x128

    seg_kernel<<<BN, SN, 0, stream>>>(dones, seg);

    // weight conversion (bf16, transposed)
    {
        dim3 tb(32,8,1);
        dim3 gEE(16,16,4);
        wconv_kernel<<<gEE, tb, 0, stream>>>(wq,  wqT, EN, EN);
        wconv_kernel<<<gEE, tb, 0, stream>>>(wk,  wkT, EN, EN);
        wconv_kernel<<<gEE, tb, 0, stream>>>(wv,  wvT, EN, EN);
        wconv_kernel<<<gEE, tb, 0, stream>>>(wg,  wgT, EN, EN);
        wconv_kernel<<<gEE, tb, 0, stream>>>(wo,  woT, EN, EN);
        wconv_kernel<<<gEE, tb, 0, stream>>>(swg, sgT, EN, EN);
        wconv_kernel<<<gEE, tb, 0, stream>>>(swl, slT, EN, EN);
        wconv_kernel<<<gEE, tb, 0, stream>>>(swo, soT, EN, EN);
        wconv_kernel<<<dim3(16,4,1),  tb, 0, stream>>>(w_enc, wencT, OBSN, EN);
        wconv_kernel<<<dim3(16,16,1), tb, 0, stream>>>(hw1,   w1T,   EN, EN);
    }

    // encoder: x = gelu(rmsnorm(obs) @ w_enc)
    rmsnorm_kernel<OBSN,false,true><<<NR/4, 256, 0, stream>>>(obs, ln_enc, nullptr, encb);
    launch_gemm(encb, wencT, nullptr, nullptr, out_x, OBSN, 1.f, 2, stream);

    for (int l=0; l<LN; ++l){
        rmsnorm_kernel<EN,true,true><<<NR/4, 256, 0, stream>>>(out_x, ln_shared, XIN, S1b);
        launch_gemm(S1b, wqT + l*WEm, nullptr, nullptr, Qb, EN, 1.f,    0, stream);
        launch_gemm(S1b, wkT + l*WEm, nullptr, nullptr, Kb, EN, 0.125f, 0, stream);
        launch_gemm(S1b, wvT + l*WEm, nullptr, nullptr, Vb, EN, 1.f,    0, stream);
        launch_gemm(S1b, wgT + l*WEm, nullptr, nullptr, Gb, EN, 1.f,    1, stream);
        retention_kernel<<<dim3(SN/16, BN*HN), 256, 0, stream>>>(
            Qb, Kb, Vb, hstate, tsid, seg, gns + l*EN, gnb + l*EN, Yb, l);
        hnew_partial<<<dim3(BN*HN, 8), 256, 0, stream>>>(Kb, Vb, tsid, seg, hpart);
        hreduce_kernel<<<BN*HN, 1024, 0, stream>>>(hpart, hstate, tsid, seg, out_h, l);
        mulb_kernel<<<NB/1024, 256, 0, stream>>>(Gb, Yb, S2b);               // silu(g)*y -> bf16
        launch_gemm(S2b, woT + l*WEm, nullptr, XIN, Qb, EN, 1.f, 0, stream); // Qb = G@wo + xin
        rmsnorm_kernel<EN,true,true><<<NR/4, 256, 0, stream>>>(Qb, ln1 + l*EN, Kb, S1b); // x1
        launch_gemm(S1b, sgT + l*WEm, nullptr, nullptr, Vb, EN, 1.f, 1, stream); // silu gate
        launch_gemm(S1b, slT + l*WEm, nullptr, nullptr, Gb, EN, 1.f, 0, stream); // lin
        mulb_kernel<<<NB/1024, 256, 0, stream>>>(Vb, Gb, S2b);               // t -> bf16
        launch_gemm(S2b, soT + l*WEm, nullptr, Kb, Qb, EN, 1.f, 0, stream);  // Qb = t@swo + x1
        if (l == LN-1)
            rmsnorm_kernel<EN,true,true ><<<NR/4, 256, 0, stream>>>(Qb, ln2 + l*EN, out_x, S1b);
        else
            rmsnorm_kernel<EN,true,false><<<NR/4, 256, 0, stream>>>(Qb, ln2 + l*EN, out_x, nullptr);
    }

    // head
    launch_gemm(S1b, w1T, hb1, nullptr, Yb, EN, 1.f, 2, stream);             // z = gelu(x@w1+b1)
    rmsnorm_kernel<EN,true,false><<<NR/4, 256, 0, stream>>>(Yb, hln, XIN, nullptr);
    vloc_kernel<<<NR/4, 256, 0, stream>>>(XIN, hw2, hb2, out_v);
}

// Round 3
// 675.175 us; speedup vs baseline: 3.8363x; 2.1744x over previous
//
#include <hip/hip_runtime.h>
#include <math.h>

#define BN 4
#define SN 1024
#define EN 512
#define HN 8
#define LN 4
#define DN 64
#define OBSN 128
#define NR (BN*SN)            // 4096 rows
#define NB (NR*EN)            // elements per activation buffer
#define EPSF 1e-6f

typedef __attribute__((ext_vector_type(8))) short short8v;
typedef __attribute__((ext_vector_type(4))) float f32x4;

__device__ __forceinline__ float logk_of(int h){
    const float start = -3.4657359027997265f;   // log(1/32)
    const float step  = -0.3960841031771117f;   // (log(1/512)-log(1/32))/7
    return logf(1.0f - expf(start + step*(float)h));
}
__device__ __forceinline__ float geluf(float x){
    float x3 = x*x*x;
    return 0.5f*x*(1.0f + tanhf(0.7978845608028654f*(x + 0.044715f*x3)));
}
__device__ __forceinline__ float siluf(float x){
    return x / (1.0f + expf(-x));
}
__device__ __forceinline__ unsigned short f2bf(float x){
    union { float f; unsigned u; } v; v.f = x;
    unsigned r = v.u + 0x7FFFu + ((v.u >> 16) & 1u);
    return (unsigned short)(r >> 16);
}
__device__ __forceinline__ void load_lds16(const void* g, void* l){
    __builtin_amdgcn_global_load_lds((const __attribute__((address_space(1))) void*)g,
                                     (__attribute__((address_space(3))) void*)l, 16, 0, 0);
}
// XOR swizzle for 64-row x 128B LDS tiles (kills stride-128B bank conflicts)
__device__ __forceinline__ int swz(int r, int bo){ return r*128 + (bo ^ ((r&7)<<4)); }

// ---------------- segment cumsum (inclusive) ----------------
__global__ void seg_kernel(const int* __restrict__ dones, int* __restrict__ seg){
    __shared__ int sm[SN];
    int b = blockIdx.x, t = threadIdx.x;
    sm[t] = dones[b*SN + t];
    __syncthreads();
    for (int off=1; off<SN; off<<=1){
        int v = (t>=off) ? sm[t-off] : 0;
        __syncthreads();
        sm[t] += v;
        __syncthreads();
    }
    seg[b*SN + t] = sm[t];
}

// ---------------- weight convert+transpose: f32 [K][M] -> bf16 [M][K] ----------------
__global__ void wconv_kernel(const float* __restrict__ src, unsigned short* __restrict__ dst,
                             int K, int M){
    __shared__ unsigned short tile[32][33];
    int mat = blockIdx.z;
    const float* s = src + (size_t)mat*K*M;
    unsigned short* d = dst + (size_t)mat*K*M;
    int k0 = blockIdx.y*32, m0 = blockIdx.x*32;
    int tx = threadIdx.x, ty = threadIdx.y;   // 32, 8
    #pragma unroll
    for (int i=0;i<32;i+=8)
        tile[tx][ty+i] = f2bf(s[(size_t)(k0+ty+i)*M + m0+tx]);
    __syncthreads();
    #pragma unroll
    for (int i=0;i<32;i+=8)
        d[(size_t)(m0+ty+i)*K + k0+tx] = tile[ty+i][tx];
}

// ---------------- rmsnorm (one wave per row), optional f32 + bf16 outputs ----------------
template<int COLS, bool WF32, bool WBF>
__global__ void rmsnorm_kernel(const float* __restrict__ A,
                               const float* __restrict__ scale,
                               float* __restrict__ Of,
                               unsigned short* __restrict__ Ob){
    constexpr int PER = COLS/64;
    int row  = blockIdx.x*4 + (threadIdx.x>>6);
    int lane = threadIdx.x & 63;
    const float* a = A + (size_t)row*COLS;
    float v[PER];
    float ss = 0.f;
    #pragma unroll
    for (int i=0;i<PER;i++){
        float x = a[lane + i*64];
        v[i] = x; ss += x*x;
    }
    #pragma unroll
    for (int off=32; off>0; off>>=1) ss += __shfl_xor(ss, off, 64);
    float rs = rsqrtf(ss*(1.0f/COLS) + EPSF);
    #pragma unroll
    for (int i=0;i<PER;i++){
        float o = v[i]*rs*scale[lane + i*64];
        if (WF32) Of[(size_t)row*COLS + lane + i*64] = o;
        if (WBF)  Ob[(size_t)row*COLS + lane + i*64] = f2bf(o);
    }
}

// ---------------- bf16 MFMA GEMM ----------------
// A bf16 [NR][K], Wt bf16 [512][K]. BM=BN=64, BK=64. 256 threads, 4 waves 2x2.
// OUTM bit0: f32 C row-major; bit1: bf16 Ob row-major; bit2: bf16 Ot transposed [b][col][s]
template<int ACT, bool BIASF, bool RESF, int OUTM>
__global__ __launch_bounds__(256) void gemm_bf16(
    const unsigned short* __restrict__ A,
    const unsigned short* __restrict__ Wt,
    const float* __restrict__ bias, const float* __restrict__ res,
    float* __restrict__ C, unsigned short* __restrict__ Ob,
    unsigned short* __restrict__ Ot, int K, float scale)
{
    __shared__ unsigned short As[64*64 + 64*64];
    unsigned short* Bs = As + 64*64;
    int t = threadIdx.x;
    int row0 = blockIdx.y*64, col0 = blockIdx.x*64;
    int w = t>>6, lane = t&63;
    int wr = w>>1, wc = w&1;
    f32x4 acc[2][2];
    #pragma unroll
    for (int m=0;m<2;m++)
        #pragma unroll
        for (int n=0;n<2;n++){ acc[m][n][0]=0.f; acc[m][n][1]=0.f; acc[m][n][2]=0.f; acc[m][n][3]=0.f; }

    for (int k0=0; k0<K; k0+=64){
        #pragma unroll
        for (int i=0;i<2;i++){
            int o = i*4096 + t*16;
            int arow = o>>7, acolb = o&127;
            load_lds16(A + (size_t)(row0+arow)*K + k0 + (acolb>>1), (char*)As + o);
        }
        #pragma unroll
        for (int i=0;i<2;i++){
            int o = i*4096 + t*16;
            int brow = o>>7, bcolb = o&127;
            load_lds16(Wt + (size_t)(col0+brow)*K + k0 + (bcolb>>1), (char*)Bs + o);
        }
        __syncthreads();
        #pragma unroll
        for (int kk=0; kk<64; kk+=32){
            int kb = kk + (lane>>4)*8;
            short8v a[2], b[2];
            #pragma unroll
            for (int m=0;m<2;m++){
                int arow = wr*32 + m*16 + (lane&15);
                a[m] = *(const short8v*)((const char*)As + arow*128 + kb*2);
            }
            #pragma unroll
            for (int n=0;n<2;n++){
                int bcol = wc*32 + n*16 + (lane&15);
                b[n] = *(const short8v*)((const char*)Bs + bcol*128 + kb*2);
            }
            #pragma unroll
            for (int m=0;m<2;m++)
                #pragma unroll
                for (int n=0;n<2;n++)
                    acc[m][n] = __builtin_amdgcn_mfma_f32_16x16x32_bf16(a[m], b[n], acc[m][n], 0,0,0);
        }
        __syncthreads();
    }
    #pragma unroll
    for (int m=0;m<2;m++){
        #pragma unroll
        for (int n=0;n<2;n++){
            int col = col0 + wc*32 + n*16 + (lane&15);
            int rbase = row0 + wr*32 + m*16 + (lane>>4)*4;
            float vals[4];
            #pragma unroll
            for (int j=0;j<4;j++){
                float x = acc[m][n][j]*scale;
                if (BIASF) x += bias[col];
                if (ACT==1) x = siluf(x);
                if (ACT==2) x = geluf(x);
                if (RESF) x += res[(size_t)(rbase+j)*512 + col];
                vals[j] = x;
                if (OUTM&1) C[(size_t)(rbase+j)*512 + col] = x;
                if (OUTM&2) Ob[(size_t)(rbase+j)*512 + col] = f2bf(x);
            }
            if (OUTM&4){
                ushort4 pk;
                pk.x=f2bf(vals[0]); pk.y=f2bf(vals[1]); pk.z=f2bf(vals[2]); pk.w=f2bf(vals[3]);
                int bb = rbase>>10;          // SN=1024
                int s0 = rbase&1023;
                *(ushort4*)(Ot + ((size_t)bb*EN + col)*SN + s0) = pk;
            }
        }
    }
}

// ---------------- elementwise multiply -> bf16 ----------------
__global__ void mulb_kernel(const float* __restrict__ A, const float* __restrict__ Bv,
                            unsigned short* __restrict__ O){
    int i = blockIdx.x*blockDim.x + threadIdx.x;
    float4 a = ((const float4*)A)[i];
    float4 b = ((const float4*)Bv)[i];
    ushort4 o;
    o.x = f2bf(a.x*b.x); o.y = f2bf(a.y*b.y);
    o.z = f2bf(a.z*b.z); o.w = f2bf(a.w*b.w);
    ((ushort4*)O)[i] = o;
}

// ---------------- MFMA retention: ret = inner + cross, fused groupnorm -> Y ----------------
// grid (16, B*H) reversed tile order; 256 threads = 4 waves; q-tile 64 rows, m-tiles 64.
__global__ __launch_bounds__(256) void retention_mfma(
    const unsigned short* __restrict__ Qbb, const unsigned short* __restrict__ Kbb,
    const unsigned short* __restrict__ VtT,
    const float* __restrict__ hstate, const int* __restrict__ tsid, const int* __restrict__ seg,
    const float* __restrict__ gns, const float* __restrict__ gnb,
    float* __restrict__ Y, int layer)
{
    int bh = blockIdx.y; int b = bh>>3; int h = bh&7;
    int tile = (int)gridDim.x - 1 - (int)blockIdx.x;   // heavy blocks first
    int n0 = tile*64;
    int t = threadIdx.x, lane = t&63, w = t>>6;
    __shared__ unsigned short Qs[64*64];
    __shared__ unsigned short Ks[64*64];
    __shared__ unsigned short Vts[64*64];
    __shared__ unsigned short Ps[64*64];   // doubles as Hs (transposed h0) for cross term
    __shared__ float tsq_s[64], eq_s[64], xi_s[64];
    __shared__ int   segq_s[64];
    __shared__ float tsm_s[64], em_s[64];
    __shared__ int   segm_s[64];
    float lk = logk_of(h);

    // stage Q tile (swizzled)
    #pragma unroll
    for (int i=0;i<2;i++){
        int c = t + i*256; int r = c>>3, cb = (c&7)*16;
        short8v qv = *(const short8v*)(Qbb + (size_t)(b*SN + n0 + r)*EN + h*DN + (cb>>1));
        *(short8v*)((char*)Qs + swz(r,cb)) = qv;
    }
    // stage Hs = h0^T (f32 [d][e] -> bf16 [e][d]) into Ps region
    const float* h0 = hstate + ((size_t)bh*LN + layer)*4096;
    #pragma unroll
    for (int i=0;i<4;i++){
        int idx = t + i*256; int d = idx>>4, e0 = (idx&15)*4;
        float4 hv = *(const float4*)(h0 + d*64 + e0);
        *(unsigned short*)((char*)Ps + swz(e0+0, 2*d)) = f2bf(hv.x);
        *(unsigned short*)((char*)Ps + swz(e0+1, 2*d)) = f2bf(hv.y);
        *(unsigned short*)((char*)Ps + swz(e0+2, 2*d)) = f2bf(hv.z);
        *(unsigned short*)((char*)Ps + swz(e0+3, 2*d)) = f2bf(hv.w);
    }
    if (t<64){
        float tq = (float)tsid[b*SN+n0+t];
        int sg = seg[b*SN+n0+t];
        tsq_s[t]=tq; segq_s[t]=sg;
        eq_s[t]=expf(tq*lk);
        xi_s[t]=(sg==0)?expf((tq+1.f)*lk):0.f;
    }
    __syncthreads();

    // per-thread q-row constants (4 rows per lane)
    int qlj = w*16 + ((lane>>4)<<2);
    float tsq_r[4], eq_r[4], xi_r[4]; int sgq_r[4];
    #pragma unroll
    for (int j=0;j<4;j++){
        tsq_r[j]=tsq_s[qlj+j]; eq_r[j]=eq_s[qlj+j];
        xi_r[j]=xi_s[qlj+j];  sgq_r[j]=segq_s[qlj+j];
    }
    // Q A-fragments (constant for whole kernel)
    short8v aq0 = *(short8v*)((char*)Qs + swz(w*16+(lane&15), (lane>>4)*16));
    short8v aq1 = *(short8v*)((char*)Qs + swz(w*16+(lane&15), 64 + (lane>>4)*16));

    // cross term: oacc = xi[q] * (Q @ h0)
    f32x4 oacc[4];
    {
        f32x4 cacc[4];
        #pragma unroll
        for (int en=0;en<4;en++){ cacc[en][0]=0.f; cacc[en][1]=0.f; cacc[en][2]=0.f; cacc[en][3]=0.f; }
        #pragma unroll
        for (int en=0;en<4;en++){
            short8v b0 = *(short8v*)((char*)Ps + swz(en*16+(lane&15), (lane>>4)*16));
            short8v b1 = *(short8v*)((char*)Ps + swz(en*16+(lane&15), 64+(lane>>4)*16));
            cacc[en] = __builtin_amdgcn_mfma_f32_16x16x32_bf16(aq0, b0, cacc[en], 0,0,0);
            cacc[en] = __builtin_amdgcn_mfma_f32_16x16x32_bf16(aq1, b1, cacc[en], 0,0,0);
        }
        #pragma unroll
        for (int en=0;en<4;en++)
            #pragma unroll
            for (int j=0;j<4;j++) oacc[en][j] = cacc[en][j]*xi_r[j];
    }

    // m-tile loop (timestep-causal: tiles 0..tile, exact elementwise mask)
    for (int mt=0; mt<=tile; ++mt){
        int m0 = mt*64;
        __syncthreads();   // protect K/V/P staging vs previous readers (and Hs reads, iter 0)
        #pragma unroll
        for (int i=0;i<2;i++){
            int c = t + i*256; int r = c>>3, cb = (c&7)*16;
            short8v kv = *(const short8v*)(Kbb + (size_t)(b*SN+m0+r)*EN + h*DN + (cb>>1));
            *(short8v*)((char*)Ks + swz(r,cb)) = kv;
            short8v vv = *(const short8v*)(VtT + ((size_t)(b*EN) + h*DN + r)*SN + m0 + (cb>>1));
            *(short8v*)((char*)Vts + swz(r,cb)) = vv;
        }
        if (t<64){
            float tm = (float)tsid[b*SN+m0+t];
            tsm_s[t]=tm; segm_s[t]=seg[b*SN+m0+t]; em_s[t]=expf(-tm*lk);
        }
        __syncthreads();
        // S = Q @ K^T
        f32x4 sacc[4];
        #pragma unroll
        for (int mn=0;mn<4;mn++){ sacc[mn][0]=0.f; sacc[mn][1]=0.f; sacc[mn][2]=0.f; sacc[mn][3]=0.f; }
        #pragma unroll
        for (int mn=0;mn<4;mn++){
            short8v b0 = *(short8v*)((char*)Ks + swz(mn*16+(lane&15), (lane>>4)*16));
            short8v b1 = *(short8v*)((char*)Ks + swz(mn*16+(lane&15), 64+(lane>>4)*16));
            sacc[mn] = __builtin_amdgcn_mfma_f32_16x16x32_bf16(aq0, b0, sacc[mn], 0,0,0);
            sacc[mn] = __builtin_amdgcn_mfma_f32_16x16x32_bf16(aq1, b1, sacc[mn], 0,0,0);
        }
        // decay + mask, P -> bf16 LDS (each wave writes only its own 16-row strip)
        #pragma unroll
        for (int mn=0;mn<4;mn++){
            int m = mn*16 + (lane&15);
            float tm = tsm_s[m]; float em = em_s[m]; int sgm = segm_s[m];
            #pragma unroll
            for (int j=0;j<4;j++){
                float p = (tsq_r[j]>=tm && sgq_r[j]==sgm) ? sacc[mn][j]*eq_r[j]*em : 0.f;
                *(unsigned short*)((char*)Ps + swz(qlj+j, 2*m)) = f2bf(p);
            }
        }
        // PV accumulate (A-frags from own strip — intra-wave dependency only)
        short8v ap0 = *(short8v*)((char*)Ps + swz(w*16+(lane&15), (lane>>4)*16));
        short8v ap1 = *(short8v*)((char*)Ps + swz(w*16+(lane&15), 64+(lane>>4)*16));
        #pragma unroll
        for (int dn=0;dn<4;dn++){
            short8v b0 = *(short8v*)((char*)Vts + swz(dn*16+(lane&15), (lane>>4)*16));
            short8v b1 = *(short8v*)((char*)Vts + swz(dn*16+(lane&15), 64+(lane>>4)*16));
            oacc[dn] = __builtin_amdgcn_mfma_f32_16x16x32_bf16(ap0, b0, oacc[dn], 0,0,0);
            oacc[dn] = __builtin_amdgcn_mfma_f32_16x16x32_bf16(ap1, b1, oacc[dn], 0,0,0);
        }
    }

    // fused groupnorm over D=64 per q-row (reduce across the 16 lanes holding the row)
    float mu[4], rs[4];
    #pragma unroll
    for (int j=0;j<4;j++){
        float s = oacc[0][j]+oacc[1][j]+oacc[2][j]+oacc[3][j];
        #pragma unroll
        for (int off=1; off<16; off<<=1) s += __shfl_xor(s, off, 64);
        mu[j] = s*(1.0f/64.0f);
        float d0=oacc[0][j]-mu[j], d1=oacc[1][j]-mu[j], d2=oacc[2][j]-mu[j], d3=oacc[3][j]-mu[j];
        float q2 = d0*d0+d1*d1+d2*d2+d3*d3;
        #pragma unroll
        for (int off=1; off<16; off<<=1) q2 += __shfl_xor(q2, off, 64);
        rs[j] = rsqrtf(q2*(1.0f/64.0f) + EPSF);
    }
    #pragma unroll
    for (int dn=0;dn<4;dn++){
        int e = h*DN + dn*16 + (lane&15);
        float gs = gns[e], gb = gnb[e];
        #pragma unroll
        for (int j=0;j<4;j++){
            size_t row = (size_t)(b*SN + n0 + qlj + j);
            Y[row*EN + e] = (oacc[dn][j]-mu[j])*rs[j]*gs + gb;
        }
    }
}

// ---------------- h_new partial: sum over 8 m-tiles of eta*k x v ----------------
__global__ __launch_bounds__(256) void hnew_partial(
    const float* __restrict__ Kb, const float* __restrict__ Vb,
    const int* __restrict__ tsid, const int* __restrict__ seg,
    float* __restrict__ part)
{
    int bh = blockIdx.x; int b = bh>>3; int h = bh&7;
    int ch = blockIdx.y;
    int t = threadIdx.x;
    int r = t>>4, c = t&15;
    int d = t>>2, e0 = (t&3)*16;
    __shared__ float k_s[16][68], v_s[16][68];
    __shared__ float eta_s[16];
    float lk = logk_of(h);
    float tmax = (float)tsid[b*SN + SN-1];
    int segl = seg[b*SN + SN-1];
    float acc[16] = {};
    for (int mt=ch*8; mt<ch*8+8; ++mt){
        int m0 = mt*16;
        size_t rowM = (size_t)(b*SN + m0 + r)*EN + h*64;
        *(float4*)&k_s[r][c*4] = *(const float4*)(Kb + rowM + c*4);
        *(float4*)&v_s[r][c*4] = *(const float4*)(Vb + rowM + c*4);
        if (t<16){
            float tsm = (float)tsid[b*SN+m0+t];
            eta_s[t] = (seg[b*SN+m0+t]==segl) ? expf((tmax - tsm)*lk) : 0.f;
        }
        __syncthreads();
        #pragma unroll
        for (int mm=0; mm<16; mm++){
            float ek = eta_s[mm]*k_s[mm][d];
            #pragma unroll
            for (int u=0; u<4; u++){
                float4 vv = *(float4*)&v_s[mm][e0+u*4];
                acc[u*4+0]+=ek*vv.x; acc[u*4+1]+=ek*vv.y;
                acc[u*4+2]+=ek*vv.z; acc[u*4+3]+=ek*vv.w;
            }
        }
        __syncthreads();
    }
    float* po = part + ((size_t)bh*8 + ch)*4096;
    #pragma unroll
    for (int u=0; u<4; u++)
        *(float4*)(po + d*64 + e0 + u*4) = make_float4(acc[u*4+0],acc[u*4+1],acc[u*4+2],acc[u*4+3]);
}

// ---------------- h_new reduce ----------------
__global__ void hreduce_kernel(const float* __restrict__ part, const float* __restrict__ hstate,
                               const int* __restrict__ tsid, const int* __restrict__ seg,
                               float* __restrict__ Hout, int layer){
    int bh = blockIdx.x; int b = bh>>3; int h = bh&7;
    int t = threadIdx.x;
    float lk = logk_of(h);
    float tmax = (float)tsid[b*SN + SN-1];
    int segl = seg[b*SN + SN-1];
    float hd = (segl==0) ? expf((tmax+1.0f)*lk) : 0.f;
    const float* h0 = hstate + ((size_t)bh*LN + layer)*4096;
    float* ho = Hout + ((size_t)bh*LN + layer)*4096;
    int e = t*4;
    float4 s = *(const float4*)(h0 + e);
    float4 o = make_float4(s.x*hd, s.y*hd, s.z*hd, s.w*hd);
    #pragma unroll
    for (int ch=0; ch<8; ch++){
        float4 p = *(const float4*)(part + ((size_t)bh*8 + ch)*4096 + e);
        o.x+=p.x; o.y+=p.y; o.z+=p.z; o.w+=p.w;
    }
    *(float4*)(ho + e) = o;
}

// ---------------- v_loc = ZN @ w2 + b2 (M=1) ----------------
__global__ void vloc_kernel(const float* __restrict__ ZN, const float* __restrict__ w2,
                            const float* __restrict__ b2, float* __restrict__ out){
    int row  = blockIdx.x*4 + (threadIdx.x>>6);
    int lane = threadIdx.x & 63;
    const float* z = ZN + (size_t)row*EN;
    float s = 0.f;
    #pragma unroll
    for (int i=0;i<8;i++) s += z[lane + i*64]*w2[lane + i*64];
    #pragma unroll
    for (int off=32; off>0; off>>=1) s += __shfl_xor(s, off, 64);
    if (lane==0) out[row] = s + b2[0];
}

// ---------------- host ----------------
typedef unsigned short u16;
static inline void launch_gemm(const u16* A, const u16* Wt, const float* bias,
                               const float* res, float* C, u16* Ob, u16* Ot,
                               int K, float scale, int act, int outm, hipStream_t s){
    dim3 g(8, 64), b(256,1,1);
    if (outm==2)                 gemm_bf16<0,false,false,2><<<g,b,0,s>>>(A,Wt,bias,res,C,Ob,Ot,K,scale);
    else if (outm==3)            gemm_bf16<0,false,false,3><<<g,b,0,s>>>(A,Wt,bias,res,C,Ob,Ot,K,scale);
    else if (outm==5)            gemm_bf16<0,false,false,5><<<g,b,0,s>>>(A,Wt,bias,res,C,Ob,Ot,K,scale);
    else if (bias)               gemm_bf16<2,true ,false,1><<<g,b,0,s>>>(A,Wt,bias,res,C,Ob,Ot,K,scale);
    else if (res)                gemm_bf16<0,false,true ,1><<<g,b,0,s>>>(A,Wt,bias,res,C,Ob,Ot,K,scale);
    else if (act==1)             gemm_bf16<1,false,false,1><<<g,b,0,s>>>(A,Wt,bias,res,C,Ob,Ot,K,scale);
    else if (act==2)             gemm_bf16<2,false,false,1><<<g,b,0,s>>>(A,Wt,bias,res,C,Ob,Ot,K,scale);
    else                         gemm_bf16<0,false,false,1><<<g,b,0,s>>>(A,Wt,bias,res,C,Ob,Ot,K,scale);
}

extern "C" void kernel_launch(void* const* d_in, const int* in_sizes, int n_in,
                              void* d_out, int out_size, void* d_ws, size_t ws_size,
                              hipStream_t stream){
    const float* obs       = (const float*)d_in[0];
    const float* hstate    = (const float*)d_in[1];
    const int*   dones     = (const int*)  d_in[2];
    const int*   tsid      = (const int*)  d_in[3];
    const float* ln_enc    = (const float*)d_in[4];
    const float* w_enc     = (const float*)d_in[5];
    const float* ln_shared = (const float*)d_in[6];
    const float* wq        = (const float*)d_in[7];
    const float* wk        = (const float*)d_in[8];
    const float* wv        = (const float*)d_in[9];
    const float* wg        = (const float*)d_in[10];
    const float* wo        = (const float*)d_in[11];
    const float* gns       = (const float*)d_in[12];
    const float* gnb       = (const float*)d_in[13];
    const float* ln1       = (const float*)d_in[14];
    const float* ln2       = (const float*)d_in[15];
    const float* swg       = (const float*)d_in[16];
    const float* swl       = (const float*)d_in[17];
    const float* swo       = (const float*)d_in[18];
    const float* hw1       = (const float*)d_in[19];
    const float* hb1       = (const float*)d_in[20];
    const float* hln       = (const float*)d_in[21];
    const float* hw2       = (const float*)d_in[22];
    const float* hb2       = (const float*)d_in[23];

    float* out_v = (float*)d_out;                 // (B,S,1)
    float* out_x = out_v + NR;                    // (B,S,E)
    float* out_h = out_x + (size_t)NR*EN;         // (B,H,L,D,D)

    float* ws    = (float*)d_ws;
    float* XIN   = ws + 0*(size_t)NB;
    float* Qb    = ws + 1*(size_t)NB;   // free until wo-output; VtT aliases it
    float* Kb    = ws + 2*(size_t)NB;
    float* Vb    = ws + 3*(size_t)NB;
    float* Gb    = ws + 4*(size_t)NB;
    float* Yb    = ws + 5*(size_t)NB;
    float* hpart = ws + 6*(size_t)NB;             // 32*8*4096 f32
    int*   seg   = (int*)(hpart + 32*8*4096);
    u16* wtb  = (u16*)(seg + NR);
    const size_t WEm = (size_t)EN*EN;             // 262144
    u16* wqT   = wtb;
    u16* wkT   = wqT + 4*WEm;
    u16* wvT   = wkT + 4*WEm;
    u16* wgT   = wvT + 4*WEm;
    u16* woT   = wgT + 4*WEm;
    u16* sgT   = woT + 4*WEm;
    u16* slT   = sgT + 4*WEm;
    u16* soT   = slT + 4*WEm;
    u16* wencT = soT + 4*WEm;                     // 512x128
    u16* w1T   = wencT + (size_t)EN*OBSN;
    u16* S1b   = w1T + WEm;                       // activation bf16 slot 1 (NB)
    u16* S2b   = S1b + (size_t)NB;                // activation bf16 slot 2 (NB)
    u16* encb  = S2b + (size_t)NB;                // 4096x128
    u16* Qbb   = encb + (size_t)NR*OBSN;          // bf16 Q (NB)
    u16* Kbb   = Qbb + (size_t)NB;                // bf16 K (NB)
    u16* VtT   = (u16*)Qb;                        // bf16 V transposed [B][512][S]

    seg_kernel<<<BN, SN, 0, stream>>>(dones, seg);

    // weight conversion (bf16, transposed)
    {
        dim3 tb(32,8,1);
        dim3 gEE(16,16,4);
        wconv_kernel<<<gEE, tb, 0, stream>>>(wq,  wqT, EN, EN);
        wconv_kernel<<<gEE, tb, 0, stream>>>(wk,  wkT, EN, EN);
        wconv_kernel<<<gEE, tb, 0, stream>>>(wv,  wvT, EN, EN);
        wconv_kernel<<<gEE, tb, 0, stream>>>(wg,  wgT, EN, EN);
        wconv_kernel<<<gEE, tb, 0, stream>>>(wo,  woT, EN, EN);
        wconv_kernel<<<gEE, tb, 0, stream>>>(swg, sgT, EN, EN);
        wconv_kernel<<<gEE, tb, 0, stream>>>(swl, slT, EN, EN);
        wconv_kernel<<<gEE, tb, 0, stream>>>(swo, soT, EN, EN);
        wconv_kernel<<<dim3(16,4,1),  tb, 0, stream>>>(w_enc, wencT, OBSN, EN);
        wconv_kernel<<<dim3(16,16,1), tb, 0, stream>>>(hw1,   w1T,   EN, EN);
    }

    // encoder: x = gelu(rmsnorm(obs) @ w_enc)
    rmsnorm_kernel<OBSN,false,true><<<NR/4, 256, 0, stream>>>(obs, ln_enc, nullptr, encb);
    launch_gemm(encb, wencT, nullptr, nullptr, out_x, nullptr, nullptr, OBSN, 1.f, 2, 1, stream);

    for (int l=0; l<LN; ++l){
        rmsnorm_kernel<EN,true,true><<<NR/4, 256, 0, stream>>>(out_x, ln_shared, XIN, S1b);
        launch_gemm(S1b, wqT + l*WEm, nullptr, nullptr, nullptr, Qbb, nullptr, EN, 1.f,    0, 2, stream);
        launch_gemm(S1b, wkT + l*WEm, nullptr, nullptr, Kb,      Kbb, nullptr, EN, 0.125f, 0, 3, stream);
        launch_gemm(S1b, wvT + l*WEm, nullptr, nullptr, Vb,  nullptr, VtT,     EN, 1.f,    0, 5, stream);
        launch_gemm(S1b, wgT + l*WEm, nullptr, nullptr, Gb,  nullptr, nullptr, EN, 1.f,    1, 1, stream);
        retention_mfma<<<dim3(16, BN*HN), 256, 0, stream>>>(
            Qbb, Kbb, VtT, hstate, tsid, seg, gns + l*EN, gnb + l*EN, Yb, l);
        hnew_partial<<<dim3(BN*HN, 8), 256, 0, stream>>>(Kb, Vb, tsid, seg, hpart);
        hreduce_kernel<<<BN*HN, 1024, 0, stream>>>(hpart, hstate, tsid, seg, out_h, l);
        mulb_kernel<<<NB/1024, 256, 0, stream>>>(Gb, Yb, S2b);               // silu(g)*y -> bf16
        launch_gemm(S2b, woT + l*WEm, nullptr, XIN, Qb, nullptr, nullptr, EN, 1.f, 0, 1, stream); // Qb = G@wo + xin
        rmsnorm_kernel<EN,true,true><<<NR/4, 256, 0, stream>>>(Qb, ln1 + l*EN, Kb, S1b); // x1
        launch_gemm(S1b, sgT + l*WEm, nullptr, nullptr, Vb, nullptr, nullptr, EN, 1.f, 1, 1, stream); // silu gate
        launch_gemm(S1b, slT + l*WEm, nullptr, nullptr, Gb, nullptr, nullptr, EN, 1.f, 0, 1, stream); // lin
        mulb_kernel<<<NB/1024, 256, 0, stream>>>(Vb, Gb, S2b);               // t -> bf16
        launch_gemm(S2b, soT + l*WEm, nullptr, Kb, Qb, nullptr, nullptr, EN, 1.f, 0, 1, stream);  // Qb = t@swo + x1
        if (l == LN-1)
            rmsnorm_kernel<EN,true,true ><<<NR/4, 256, 0, stream>>>(Qb, ln2 + l*EN, out_x, S1b);
        else
            rmsnorm_kernel<EN,true,false><<<NR/4, 256, 0, stream>>>(Qb, ln2 + l*EN, out_x, nullptr);
    }

    // head
    launch_gemm(S1b, w1T, hb1, nullptr, Yb, nullptr, nullptr, EN, 1.f, 2, 1, stream); // z = gelu(x@w1+b1)
    rmsnorm_kernel<EN,true,false><<<NR/4, 256, 0, stream>>>(Yb, hln, XIN, nullptr);
    vloc_kernel<<<NR/4, 256, 0, stream>>>(XIN, hw2, hb2, out_v);
}

// Round 4
// 505.388 us; speedup vs baseline: 5.1251x; 1.3360x over previous
//
#include <hip/hip_runtime.h>
#include <math.h>

#define BN 4
#define SN 1024
#define EN 512
#define HN 8
#define LN 4
#define DN 64
#define OBSN 128
#define NR (BN*SN)            // 4096 rows
#define NB (NR*EN)            // elements per activation buffer
#define EPSF 1e-6f

typedef __attribute__((ext_vector_type(8))) short short8v;
typedef __attribute__((ext_vector_type(4))) float f32x4;
typedef unsigned short u16;

__device__ __forceinline__ float logk_of(int h){
    const float start = -3.4657359027997265f;   // log(1/32)
    const float step  = -0.3960841031771117f;   // (log(1/512)-log(1/32))/7
    return logf(1.0f - expf(start + step*(float)h));
}
__device__ __forceinline__ float geluf(float x){
    float x3 = x*x*x;
    return 0.5f*x*(1.0f + tanhf(0.7978845608028654f*(x + 0.044715f*x3)));
}
__device__ __forceinline__ float siluf(float x){
    return x / (1.0f + expf(-x));
}
__device__ __forceinline__ u16 f2bf(float x){
    union { float f; unsigned u; } v; v.f = x;
    unsigned r = v.u + 0x7FFFu + ((v.u >> 16) & 1u);
    return (u16)(r >> 16);
}
__device__ __forceinline__ void load_lds16(const void* g, void* l){
    __builtin_amdgcn_global_load_lds((const __attribute__((address_space(1))) void*)g,
                                     (__attribute__((address_space(3))) void*)l, 16, 0, 0);
}
// XOR swizzle for 64-row x 128B LDS tiles
__device__ __forceinline__ int swz(int r, int bo){ return r*128 + (bo ^ ((r&7)<<4)); }

// ---------------- segment cumsum (inclusive) ----------------
__global__ void seg_kernel(const int* __restrict__ dones, int* __restrict__ seg){
    __shared__ int sm[SN];
    int b = blockIdx.x, t = threadIdx.x;
    sm[t] = dones[b*SN + t];
    __syncthreads();
    for (int off=1; off<SN; off<<=1){
        int v = (t>=off) ? sm[t-off] : 0;
        __syncthreads();
        sm[t] += v;
        __syncthreads();
    }
    seg[b*SN + t] = sm[t];
}

// ---------------- weight convert+transpose: f32 [K][M] -> bf16 [M][K] ----------------
// all 8 per-layer EE weights in one launch: z = type*4 + layer (32 blocks-z)
__global__ void wconv8_kernel(const float* w0, const float* w1, const float* w2,
                              const float* w3, const float* w4, const float* w5,
                              const float* w6, const float* w7,
                              u16* __restrict__ dst){
    __shared__ u16 tile[32][33];
    int z = blockIdx.z;
    int type = z>>2, layer = z&3;
    const float* srcs[8] = {w0,w1,w2,w3,w4,w5,w6,w7};
    const float* s = srcs[type] + (size_t)layer*EN*EN;
    u16* d = dst + ((size_t)type*LN + layer)*EN*EN;
    int k0 = blockIdx.y*32, m0 = blockIdx.x*32;
    int tx = threadIdx.x, ty = threadIdx.y;   // 32, 8
    #pragma unroll
    for (int i=0;i<32;i+=8)
        tile[tx][ty+i] = f2bf(s[(size_t)(k0+ty+i)*EN + m0+tx]);
    __syncthreads();
    #pragma unroll
    for (int i=0;i<32;i+=8)
        d[(size_t)(m0+ty+i)*EN + k0+tx] = tile[ty+i][tx];
}
__global__ void wconv_kernel(const float* __restrict__ src, u16* __restrict__ dst,
                             int K, int M){
    __shared__ u16 tile[32][33];
    const float* s = src;
    u16* d = dst;
    int k0 = blockIdx.y*32, m0 = blockIdx.x*32;
    int tx = threadIdx.x, ty = threadIdx.y;
    #pragma unroll
    for (int i=0;i<32;i+=8)
        tile[tx][ty+i] = f2bf(s[(size_t)(k0+ty+i)*M + m0+tx]);
    __syncthreads();
    #pragma unroll
    for (int i=0;i<32;i+=8)
        d[(size_t)(m0+ty+i)*K + k0+tx] = tile[ty+i][tx];
}

// ---------------- rmsnorm (one wave per row), optional f32 + bf16 outputs ----------------
template<int COLS, bool WF32, bool WBF>
__global__ void rmsnorm_kernel(const float* __restrict__ A,
                               const float* __restrict__ scale,
                               float* __restrict__ Of,
                               u16* __restrict__ Ob){
    constexpr int PER = COLS/64;
    int row  = blockIdx.x*4 + (threadIdx.x>>6);
    int lane = threadIdx.x & 63;
    const float* a = A + (size_t)row*COLS;
    float v[PER];
    float ss = 0.f;
    #pragma unroll
    for (int i=0;i<PER;i++){
        float x = a[lane + i*64];
        v[i] = x; ss += x*x;
    }
    #pragma unroll
    for (int off=32; off>0; off>>=1) ss += __shfl_xor(ss, off, 64);
    float rs = rsqrtf(ss*(1.0f/COLS) + EPSF);
    #pragma unroll
    for (int i=0;i<PER;i++){
        float o = v[i]*rs*scale[lane + i*64];
        if (WF32) Of[(size_t)row*COLS + lane + i*64] = o;
        if (WBF)  Ob[(size_t)row*COLS + lane + i*64] = f2bf(o);
    }
}

// ======== shared MFMA tile helpers (BM=BN=64, BK=64, 256 thr, 4 waves 2x2) ========
struct TileCtx { int t, w, lane, wr, wc; };
__device__ __forceinline__ void stage_tileA(const u16* __restrict__ A, size_t rowBase,
                                            int K, int k0, u16* As, int t){
    #pragma unroll
    for (int i=0;i<2;i++){
        int o = i*4096 + t*16;
        int arow = o>>7, acolb = o&127;
        load_lds16(A + (rowBase+arow)*K + k0 + (acolb>>1), (char*)As + o);
    }
}
__device__ __forceinline__ void mma_tile(const u16* As, const u16* Bs, f32x4 acc[2][2],
                                         int wr, int wc, int lane){
    #pragma unroll
    for (int kk=0; kk<64; kk+=32){
        int kb = kk + (lane>>4)*8;
        short8v a[2], b[2];
        #pragma unroll
        for (int m=0;m<2;m++)
            a[m] = *(const short8v*)((const char*)As + (wr*32+m*16+(lane&15))*128 + kb*2);
        #pragma unroll
        for (int n=0;n<2;n++)
            b[n] = *(const short8v*)((const char*)Bs + (wc*32+n*16+(lane&15))*128 + kb*2);
        #pragma unroll
        for (int m=0;m<2;m++)
            #pragma unroll
            for (int n=0;n<2;n++)
                acc[m][n] = __builtin_amdgcn_mfma_f32_16x16x32_bf16(a[m], b[n], acc[m][n], 0,0,0);
    }
}
#define ZERO_ACC(acc) { _Pragma("unroll") for (int m=0;m<2;m++) _Pragma("unroll") for (int n=0;n<2;n++){ acc[m][n][0]=0.f;acc[m][n][1]=0.f;acc[m][n][2]=0.f;acc[m][n][3]=0.f; } }

// ---------------- fused QKVG GEMM ----------------
// A bf16 [NR][512]; 4 weights bf16 [512][512] (col-major-K). grid (8, 64).
__global__ __launch_bounds__(256) void gemm_qkvg(
    const u16* __restrict__ A,
    const u16* __restrict__ WQ, const u16* __restrict__ WK,
    const u16* __restrict__ WV, const u16* __restrict__ WG,
    u16* __restrict__ Qbb, float* __restrict__ Kb, u16* __restrict__ Kbb,
    float* __restrict__ Vb, u16* __restrict__ VtT, float* __restrict__ Gb)
{
    __shared__ u16 As[64*64];
    __shared__ u16 Bs[4][64*64];
    int t = threadIdx.x;
    int row0 = blockIdx.y*64, col0 = blockIdx.x*64;
    int w = t>>6, lane = t&63;
    int wr = w>>1, wc = w&1;
    f32x4 accQ[2][2], accK[2][2], accV[2][2], accG[2][2];
    ZERO_ACC(accQ); ZERO_ACC(accK); ZERO_ACC(accV); ZERO_ACC(accG);
    const u16* Ws[4] = {WQ, WK, WV, WG};

    for (int k0=0; k0<EN; k0+=64){
        stage_tileA(A, (size_t)row0, EN, k0, As, t);
        #pragma unroll
        for (int wt=0; wt<4; wt++){
            #pragma unroll
            for (int i=0;i<2;i++){
                int o = i*4096 + t*16;
                int brow = o>>7, bcolb = o&127;
                load_lds16(Ws[wt] + (size_t)(col0+brow)*EN + k0 + (bcolb>>1), (char*)Bs[wt] + o);
            }
        }
        __syncthreads();
        mma_tile(As, Bs[0], accQ, wr, wc, lane);
        mma_tile(As, Bs[1], accK, wr, wc, lane);
        mma_tile(As, Bs[2], accV, wr, wc, lane);
        mma_tile(As, Bs[3], accG, wr, wc, lane);
        __syncthreads();
    }
    #pragma unroll
    for (int m=0;m<2;m++){
        #pragma unroll
        for (int n=0;n<2;n++){
            int col = col0 + wc*32 + n*16 + (lane&15);
            int rbase = row0 + wr*32 + m*16 + (lane>>4)*4;
            float vv[4];
            #pragma unroll
            for (int j=0;j<4;j++){
                size_t idx = (size_t)(rbase+j)*EN + col;
                Qbb[idx] = f2bf(accQ[m][n][j]);
                float kx = accK[m][n][j]*0.125f;
                Kb[idx] = kx; Kbb[idx] = f2bf(kx);
                float vx = accV[m][n][j];
                Vb[idx] = vx; vv[j] = vx;
                Gb[idx] = siluf(accG[m][n][j]);
            }
            ushort4 pk;
            pk.x=f2bf(vv[0]); pk.y=f2bf(vv[1]); pk.z=f2bf(vv[2]); pk.w=f2bf(vv[3]);
            int bb = rbase>>10;
            int s0 = rbase&1023;
            *(ushort4*)(VtT + ((size_t)bb*EN + col)*SN + s0) = pk;
        }
    }
}

// ---------------- fused swiglu pair: S2b = bf16(silu(A@Wg) * (A@Wl)) ----------------
__global__ __launch_bounds__(256) void gemm_swpair(
    const u16* __restrict__ A,
    const u16* __restrict__ WGt, const u16* __restrict__ WLt,
    u16* __restrict__ Out)
{
    __shared__ u16 As[64*64];
    __shared__ u16 Bg[64*64];
    __shared__ u16 Bl[64*64];
    int t = threadIdx.x;
    int row0 = blockIdx.y*64, col0 = blockIdx.x*64;
    int w = t>>6, lane = t&63;
    int wr = w>>1, wc = w&1;
    f32x4 accG[2][2], accL[2][2];
    ZERO_ACC(accG); ZERO_ACC(accL);
    for (int k0=0; k0<EN; k0+=64){
        stage_tileA(A, (size_t)row0, EN, k0, As, t);
        #pragma unroll
        for (int i=0;i<2;i++){
            int o = i*4096 + t*16;
            int brow = o>>7, bcolb = o&127;
            load_lds16(WGt + (size_t)(col0+brow)*EN + k0 + (bcolb>>1), (char*)Bg + o);
            load_lds16(WLt + (size_t)(col0+brow)*EN + k0 + (bcolb>>1), (char*)Bl + o);
        }
        __syncthreads();
        mma_tile(As, Bg, accG, wr, wc, lane);
        mma_tile(As, Bl, accL, wr, wc, lane);
        __syncthreads();
    }
    #pragma unroll
    for (int m=0;m<2;m++){
        #pragma unroll
        for (int n=0;n<2;n++){
            int col = col0 + wc*32 + n*16 + (lane&15);
            int rbase = row0 + wr*32 + m*16 + (lane>>4)*4;
            #pragma unroll
            for (int j=0;j<4;j++){
                float x = siluf(accG[m][n][j]) * accL[m][n][j];
                Out[(size_t)(rbase+j)*EN + col] = f2bf(x);
            }
        }
    }
}

// ---------------- plain bf16 GEMM (wo/swo/enc/head) ----------------
// OUTM bit0: f32 C; bit1: bf16 Ob
template<int ACT, bool BIASF, bool RESF, int OUTM>
__global__ __launch_bounds__(256) void gemm_bf16(
    const u16* __restrict__ A, const u16* __restrict__ Wt,
    const float* __restrict__ bias, const float* __restrict__ res,
    float* __restrict__ C, u16* __restrict__ Ob, int K, float scale)
{
    __shared__ u16 As[64*64];
    __shared__ u16 Bs[64*64];
    int t = threadIdx.x;
    int row0 = blockIdx.y*64, col0 = blockIdx.x*64;
    int w = t>>6, lane = t&63;
    int wr = w>>1, wc = w&1;
    f32x4 acc[2][2];
    ZERO_ACC(acc);
    for (int k0=0; k0<K; k0+=64){
        stage_tileA(A, (size_t)row0, K, k0, As, t);
        #pragma unroll
        for (int i=0;i<2;i++){
            int o = i*4096 + t*16;
            int brow = o>>7, bcolb = o&127;
            load_lds16(Wt + (size_t)(col0+brow)*K + k0 + (bcolb>>1), (char*)Bs + o);
        }
        __syncthreads();
        mma_tile(As, Bs, acc, wr, wc, lane);
        __syncthreads();
    }
    #pragma unroll
    for (int m=0;m<2;m++){
        #pragma unroll
        for (int n=0;n<2;n++){
            int col = col0 + wc*32 + n*16 + (lane&15);
            int rbase = row0 + wr*32 + m*16 + (lane>>4)*4;
            #pragma unroll
            for (int j=0;j<4;j++){
                float x = acc[m][n][j]*scale;
                if (BIASF) x += bias[col];
                if (ACT==1) x = siluf(x);
                if (ACT==2) x = geluf(x);
                if (RESF) x += res[(size_t)(rbase+j)*512 + col];
                if (OUTM&1) C[(size_t)(rbase+j)*512 + col] = x;
                if (OUTM&2) Ob[(size_t)(rbase+j)*512 + col] = f2bf(x);
            }
        }
    }
}

// ---------------- MFMA retention + fused groupnorm + fused gate-mul ----------------
// grid (16, B*H) reversed; 256 threads, 4 waves; q-tile 64, m-tiles 64.
__global__ __launch_bounds__(256) void retention_mfma(
    const u16* __restrict__ Qbb, const u16* __restrict__ Kbb,
    const u16* __restrict__ VtT,
    const float* __restrict__ hstate, const int* __restrict__ tsid, const int* __restrict__ seg,
    const float* __restrict__ gns, const float* __restrict__ gnb,
    const float* __restrict__ Gb, u16* __restrict__ Out, int layer)
{
    int bh = blockIdx.y; int b = bh>>3; int h = bh&7;
    int tile = (int)gridDim.x - 1 - (int)blockIdx.x;
    int n0 = tile*64;
    int t = threadIdx.x, lane = t&63, w = t>>6;
    __shared__ u16 Qs[64*64];
    __shared__ u16 Ks[64*64];
    __shared__ u16 Vts[64*64];
    __shared__ u16 Ps[64*64];
    __shared__ float tsq_s[64], eq_s[64], xi_s[64];
    __shared__ int   segq_s[64];
    __shared__ float tsm_s[64], em_s[64];
    __shared__ int   segm_s[64];
    float lk = logk_of(h);

    #pragma unroll
    for (int i=0;i<2;i++){
        int c = t + i*256; int r = c>>3, cb = (c&7)*16;
        short8v qv = *(const short8v*)(Qbb + (size_t)(b*SN + n0 + r)*EN + h*DN + (cb>>1));
        *(short8v*)((char*)Qs + swz(r,cb)) = qv;
    }
    const float* h0 = hstate + ((size_t)bh*LN + layer)*4096;
    #pragma unroll
    for (int i=0;i<4;i++){
        int idx = t + i*256; int d = idx>>4, e0 = (idx&15)*4;
        float4 hv = *(const float4*)(h0 + d*64 + e0);
        *(u16*)((char*)Ps + swz(e0+0, 2*d)) = f2bf(hv.x);
        *(u16*)((char*)Ps + swz(e0+1, 2*d)) = f2bf(hv.y);
        *(u16*)((char*)Ps + swz(e0+2, 2*d)) = f2bf(hv.z);
        *(u16*)((char*)Ps + swz(e0+3, 2*d)) = f2bf(hv.w);
    }
    if (t<64){
        float tq = (float)tsid[b*SN+n0+t];
        int sg = seg[b*SN+n0+t];
        tsq_s[t]=tq; segq_s[t]=sg;
        eq_s[t]=expf(tq*lk);
        xi_s[t]=(sg==0)?expf((tq+1.f)*lk):0.f;
    }
    __syncthreads();

    int qlj = w*16 + ((lane>>4)<<2);
    float tsq_r[4], eq_r[4], xi_r[4]; int sgq_r[4];
    #pragma unroll
    for (int j=0;j<4;j++){
        tsq_r[j]=tsq_s[qlj+j]; eq_r[j]=eq_s[qlj+j];
        xi_r[j]=xi_s[qlj+j];  sgq_r[j]=segq_s[qlj+j];
    }
    short8v aq0 = *(short8v*)((char*)Qs + swz(w*16+(lane&15), (lane>>4)*16));
    short8v aq1 = *(short8v*)((char*)Qs + swz(w*16+(lane&15), 64 + (lane>>4)*16));

    f32x4 oacc[4];
    {
        f32x4 cacc[4];
        #pragma unroll
        for (int en=0;en<4;en++){ cacc[en][0]=0.f; cacc[en][1]=0.f; cacc[en][2]=0.f; cacc[en][3]=0.f; }
        #pragma unroll
        for (int en=0;en<4;en++){
            short8v b0 = *(short8v*)((char*)Ps + swz(en*16+(lane&15), (lane>>4)*16));
            short8v b1 = *(short8v*)((char*)Ps + swz(en*16+(lane&15), 64+(lane>>4)*16));
            cacc[en] = __builtin_amdgcn_mfma_f32_16x16x32_bf16(aq0, b0, cacc[en], 0,0,0);
            cacc[en] = __builtin_amdgcn_mfma_f32_16x16x32_bf16(aq1, b1, cacc[en], 0,0,0);
        }
        #pragma unroll
        for (int en=0;en<4;en++)
            #pragma unroll
            for (int j=0;j<4;j++) oacc[en][j] = cacc[en][j]*xi_r[j];
    }

    for (int mt=0; mt<=tile; ++mt){
        int m0 = mt*64;
        __syncthreads();
        #pragma unroll
        for (int i=0;i<2;i++){
            int c = t + i*256; int r = c>>3, cb = (c&7)*16;
            short8v kv = *(const short8v*)(Kbb + (size_t)(b*SN+m0+r)*EN + h*DN + (cb>>1));
            *(short8v*)((char*)Ks + swz(r,cb)) = kv;
            short8v vv = *(const short8v*)(VtT + ((size_t)(b*EN) + h*DN + r)*SN + m0 + (cb>>1));
            *(short8v*)((char*)Vts + swz(r,cb)) = vv;
        }
        if (t<64){
            float tm = (float)tsid[b*SN+m0+t];
            tsm_s[t]=tm; segm_s[t]=seg[b*SN+m0+t]; em_s[t]=expf(-tm*lk);
        }
        __syncthreads();
        f32x4 sacc[4];
        #pragma unroll
        for (int mn=0;mn<4;mn++){ sacc[mn][0]=0.f; sacc[mn][1]=0.f; sacc[mn][2]=0.f; sacc[mn][3]=0.f; }
        #pragma unroll
        for (int mn=0;mn<4;mn++){
            short8v b0 = *(short8v*)((char*)Ks + swz(mn*16+(lane&15), (lane>>4)*16));
            short8v b1 = *(short8v*)((char*)Ks + swz(mn*16+(lane&15), 64+(lane>>4)*16));
            sacc[mn] = __builtin_amdgcn_mfma_f32_16x16x32_bf16(aq0, b0, sacc[mn], 0,0,0);
            sacc[mn] = __builtin_amdgcn_mfma_f32_16x16x32_bf16(aq1, b1, sacc[mn], 0,0,0);
        }
        #pragma unroll
        for (int mn=0;mn<4;mn++){
            int m = mn*16 + (lane&15);
            float tm = tsm_s[m]; float em = em_s[m]; int sgm = segm_s[m];
            #pragma unroll
            for (int j=0;j<4;j++){
                float p = (tsq_r[j]>=tm && sgq_r[j]==sgm) ? sacc[mn][j]*eq_r[j]*em : 0.f;
                *(u16*)((char*)Ps + swz(qlj+j, 2*m)) = f2bf(p);
            }
        }
        short8v ap0 = *(short8v*)((char*)Ps + swz(w*16+(lane&15), (lane>>4)*16));
        short8v ap1 = *(short8v*)((char*)Ps + swz(w*16+(lane&15), 64+(lane>>4)*16));
        #pragma unroll
        for (int dn=0;dn<4;dn++){
            short8v b0 = *(short8v*)((char*)Vts + swz(dn*16+(lane&15), (lane>>4)*16));
            short8v b1 = *(short8v*)((char*)Vts + swz(dn*16+(lane&15), 64+(lane>>4)*16));
            oacc[dn] = __builtin_amdgcn_mfma_f32_16x16x32_bf16(ap0, b0, oacc[dn], 0,0,0);
            oacc[dn] = __builtin_amdgcn_mfma_f32_16x16x32_bf16(ap1, b1, oacc[dn], 0,0,0);
        }
    }

    float mu[4], rs[4];
    #pragma unroll
    for (int j=0;j<4;j++){
        float s = oacc[0][j]+oacc[1][j]+oacc[2][j]+oacc[3][j];
        #pragma unroll
        for (int off=1; off<16; off<<=1) s += __shfl_xor(s, off, 64);
        mu[j] = s*(1.0f/64.0f);
        float d0=oacc[0][j]-mu[j], d1=oacc[1][j]-mu[j], d2=oacc[2][j]-mu[j], d3=oacc[3][j]-mu[j];
        float q2 = d0*d0+d1*d1+d2*d2+d3*d3;
        #pragma unroll
        for (int off=1; off<16; off<<=1) q2 += __shfl_xor(q2, off, 64);
        rs[j] = rsqrtf(q2*(1.0f/64.0f) + EPSF);
    }
    #pragma unroll
    for (int dn=0;dn<4;dn++){
        int e = h*DN + dn*16 + (lane&15);
        float gs = gns[e], gb = gnb[e];
        #pragma unroll
        for (int j=0;j<4;j++){
            size_t row = (size_t)(b*SN + n0 + qlj + j);
            float y = (oacc[dn][j]-mu[j])*rs[j]*gs + gb;
            Out[row*EN + e] = f2bf(y * Gb[row*EN + e]);
        }
    }
}

// ---------------- h_new partial: 16 chunks x 4 m-tiles ----------------
__global__ __launch_bounds__(256) void hnew_partial(
    const float* __restrict__ Kb, const float* __restrict__ Vb,
    const int* __restrict__ tsid, const int* __restrict__ seg,
    float* __restrict__ part)
{
    int bh = blockIdx.x; int b = bh>>3; int h = bh&7;
    int ch = blockIdx.y;
    int t = threadIdx.x;
    int r = t>>4, c = t&15;
    int d = t>>2, e0 = (t&3)*16;
    __shared__ float k_s[16][68], v_s[16][68];
    __shared__ float eta_s[16];
    float lk = logk_of(h);
    float tmax = (float)tsid[b*SN + SN-1];
    int segl = seg[b*SN + SN-1];
    float acc[16] = {};
    for (int mt=ch*4; mt<ch*4+4; ++mt){
        int m0 = mt*16;
        size_t rowM = (size_t)(b*SN + m0 + r)*EN + h*64;
        *(float4*)&k_s[r][c*4] = *(const float4*)(Kb + rowM + c*4);
        *(float4*)&v_s[r][c*4] = *(const float4*)(Vb + rowM + c*4);
        if (t<16){
            float tsm = (float)tsid[b*SN+m0+t];
            eta_s[t] = (seg[b*SN+m0+t]==segl) ? expf((tmax - tsm)*lk) : 0.f;
        }
        __syncthreads();
        #pragma unroll
        for (int mm=0; mm<16; mm++){
            float ek = eta_s[mm]*k_s[mm][d];
            #pragma unroll
            for (int u=0; u<4; u++){
                float4 vv = *(float4*)&v_s[mm][e0+u*4];
                acc[u*4+0]+=ek*vv.x; acc[u*4+1]+=ek*vv.y;
                acc[u*4+2]+=ek*vv.z; acc[u*4+3]+=ek*vv.w;
            }
        }
        __syncthreads();
    }
    float* po = part + ((size_t)bh*16 + ch)*4096;
    #pragma unroll
    for (int u=0; u<4; u++)
        *(float4*)(po + d*64 + e0 + u*4) = make_float4(acc[u*4+0],acc[u*4+1],acc[u*4+2],acc[u*4+3]);
}

// ---------------- h_new reduce ----------------
__global__ void hreduce_kernel(const float* __restrict__ part, const float* __restrict__ hstate,
                               const int* __restrict__ tsid, const int* __restrict__ seg,
                               float* __restrict__ Hout, int layer){
    int bh = blockIdx.x; int b = bh>>3; int h = bh&7;
    int t = threadIdx.x;
    float lk = logk_of(h);
    float tmax = (float)tsid[b*SN + SN-1];
    int segl = seg[b*SN + SN-1];
    float hd = (segl==0) ? expf((tmax+1.0f)*lk) : 0.f;
    const float* h0 = hstate + ((size_t)bh*LN + layer)*4096;
    float* ho = Hout + ((size_t)bh*LN + layer)*4096;
    int e = t*4;
    float4 s = *(const float4*)(h0 + e);
    float4 o = make_float4(s.x*hd, s.y*hd, s.z*hd, s.w*hd);
    #pragma unroll
    for (int ch=0; ch<16; ch++){
        float4 p = *(const float4*)(part + ((size_t)bh*16 + ch)*4096 + e);
        o.x+=p.x; o.y+=p.y; o.z+=p.z; o.w+=p.w;
    }
    *(float4*)(ho + e) = o;
}

// ---------------- v_loc = ZN @ w2 + b2 (M=1) ----------------
__global__ void vloc_kernel(const float* __restrict__ ZN, const float* __restrict__ w2,
                            const float* __restrict__ b2, float* __restrict__ out){
    int row  = blockIdx.x*4 + (threadIdx.x>>6);
    int lane = threadIdx.x & 63;
    const float* z = ZN + (size_t)row*EN;
    float s = 0.f;
    #pragma unroll
    for (int i=0;i<8;i++) s += z[lane + i*64]*w2[lane + i*64];
    #pragma unroll
    for (int off=32; off>0; off>>=1) s += __shfl_xor(s, off, 64);
    if (lane==0) out[row] = s + b2[0];
}

// ---------------- host ----------------
static inline void launch_gemm(const u16* A, const u16* Wt, const float* bias,
                               const float* res, float* C, u16* Ob,
                               int K, float scale, int act, int outm, hipStream_t s){
    dim3 g(8, 64), b(256,1,1);
    if (bias)                    gemm_bf16<2,true ,false,1><<<g,b,0,s>>>(A,Wt,bias,res,C,Ob,K,scale);
    else if (res && outm==3)     gemm_bf16<0,false,true ,3><<<g,b,0,s>>>(A,Wt,bias,res,C,Ob,K,scale);
    else if (res)                gemm_bf16<0,false,true ,1><<<g,b,0,s>>>(A,Wt,bias,res,C,Ob,K,scale);
    else if (act==2)             gemm_bf16<2,false,false,1><<<g,b,0,s>>>(A,Wt,bias,res,C,Ob,K,scale);
    else                         gemm_bf16<0,false,false,1><<<g,b,0,s>>>(A,Wt,bias,res,C,Ob,K,scale);
}

extern "C" void kernel_launch(void* const* d_in, const int* in_sizes, int n_in,
                              void* d_out, int out_size, void* d_ws, size_t ws_size,
                              hipStream_t stream){
    const float* obs       = (const float*)d_in[0];
    const float* hstate    = (const float*)d_in[1];
    const int*   dones     = (const int*)  d_in[2];
    const int*   tsid      = (const int*)  d_in[3];
    const float* ln_enc    = (const float*)d_in[4];
    const float* w_enc     = (const float*)d_in[5];
    const float* ln_shared = (const float*)d_in[6];
    const float* wq        = (const float*)d_in[7];
    const float* wk        = (const float*)d_in[8];
    const float* wv        = (const float*)d_in[9];
    const float* wg        = (const float*)d_in[10];
    const float* wo        = (const float*)d_in[11];
    const float* gns       = (const float*)d_in[12];
    const float* gnb       = (const float*)d_in[13];
    const float* ln1       = (const float*)d_in[14];
    const float* ln2       = (const float*)d_in[15];
    const float* swg       = (const float*)d_in[16];
    const float* swl       = (const float*)d_in[17];
    const float* swo       = (const float*)d_in[18];
    const float* hw1       = (const float*)d_in[19];
    const float* hb1       = (const float*)d_in[20];
    const float* hln       = (const float*)d_in[21];
    const float* hw2       = (const float*)d_in[22];
    const float* hb2       = (const float*)d_in[23];

    float* out_v = (float*)d_out;                 // (B,S,1)
    float* out_x = out_v + NR;                    // (B,S,E)
    float* out_h = out_x + (size_t)NR*EN;         // (B,H,L,D,D)

    float* ws    = (float*)d_ws;
    float* XIN   = ws + 0*(size_t)NB;
    float* Qb    = ws + 1*(size_t)NB;   // f32 temp; VtT aliases it
    float* Kb    = ws + 2*(size_t)NB;
    float* Vb    = ws + 3*(size_t)NB;
    float* Gb    = ws + 4*(size_t)NB;
    float* Yb    = ws + 5*(size_t)NB;
    float* hpart = ws + 6*(size_t)NB;             // 32*16*4096 f32
    int*   seg   = (int*)(hpart + 32*16*4096);
    u16* wtb  = (u16*)(seg + NR);
    const size_t WEm = (size_t)EN*EN;
    u16* wqT   = wtb;                 // type 0
    u16* wkT   = wqT + 4*WEm;         // type 1
    u16* wvT   = wkT + 4*WEm;         // type 2
    u16* wgT   = wvT + 4*WEm;         // type 3
    u16* woT   = wgT + 4*WEm;         // type 4
    u16* sgT   = woT + 4*WEm;         // type 5
    u16* slT   = sgT + 4*WEm;         // type 6
    u16* soT   = slT + 4*WEm;         // type 7
    u16* wencT = soT + 4*WEm;
    u16* w1T   = wencT + (size_t)EN*OBSN;
    u16* S1b   = w1T + WEm;
    u16* S2b   = S1b + (size_t)NB;
    u16* encb  = S2b + (size_t)NB;
    u16* Qbb   = encb + (size_t)NR*OBSN;
    u16* Kbb   = Qbb + (size_t)NB;
    u16* VtT   = (u16*)Qb;

    seg_kernel<<<BN, SN, 0, stream>>>(dones, seg);

    {
        dim3 tb(32,8,1);
        wconv8_kernel<<<dim3(16,16,32), tb, 0, stream>>>(wq,wk,wv,wg,wo,swg,swl,swo, wtb);
        wconv_kernel<<<dim3(16,4,1),  tb, 0, stream>>>(w_enc, wencT, OBSN, EN);
        wconv_kernel<<<dim3(16,16,1), tb, 0, stream>>>(hw1,   w1T,   EN, EN);
    }

    // encoder
    rmsnorm_kernel<OBSN,false,true><<<NR/4, 256, 0, stream>>>(obs, ln_enc, nullptr, encb);
    launch_gemm(encb, wencT, nullptr, nullptr, out_x, nullptr, OBSN, 1.f, 2, 1, stream);

    for (int l=0; l<LN; ++l){
        rmsnorm_kernel<EN,true,true><<<NR/4, 256, 0, stream>>>(out_x, ln_shared, XIN, S1b);
        gemm_qkvg<<<dim3(8,64), 256, 0, stream>>>(S1b,
            wqT + l*WEm, wkT + l*WEm, wvT + l*WEm, wgT + l*WEm,
            Qbb, Kb, Kbb, Vb, VtT, Gb);
        retention_mfma<<<dim3(16, BN*HN), 256, 0, stream>>>(
            Qbb, Kbb, VtT, hstate, tsid, seg, gns + l*EN, gnb + l*EN, Gb, S2b, l);
        hnew_partial<<<dim3(BN*HN, 16), 256, 0, stream>>>(Kb, Vb, tsid, seg, hpart);
        hreduce_kernel<<<BN*HN, 1024, 0, stream>>>(hpart, hstate, tsid, seg, out_h, l);
        launch_gemm(S2b, woT + l*WEm, nullptr, XIN, Qb, nullptr, EN, 1.f, 0, 1, stream); // Qb = ret@wo + xin
        rmsnorm_kernel<EN,true,true><<<NR/4, 256, 0, stream>>>(Qb, ln1 + l*EN, Kb, S1b); // x1 (f32 Kb, bf16 S1b)
        gemm_swpair<<<dim3(8,64), 256, 0, stream>>>(S1b, sgT + l*WEm, slT + l*WEm, S2b);
        launch_gemm(S2b, soT + l*WEm, nullptr, Kb, Qb, nullptr, EN, 1.f, 0, 1, stream);  // Qb = t@swo + x1
        if (l == LN-1)
            rmsnorm_kernel<EN,true,true ><<<NR/4, 256, 0, stream>>>(Qb, ln2 + l*EN, out_x, S1b);
        else
            rmsnorm_kernel<EN,true,false><<<NR/4, 256, 0, stream>>>(Qb, ln2 + l*EN, out_x, nullptr);
    }

    // head
    launch_gemm(S1b, w1T, hb1, nullptr, Yb, nullptr, EN, 1.f, 2, 1, stream);
    rmsnorm_kernel<EN,true,false><<<NR/4, 256, 0, stream>>>(Yb, hln, XIN, nullptr);
    vloc_kernel<<<NR/4, 256, 0, stream>>>(XIN, hw2, hb2, out_v);
}

// Round 5
// 436.423 us; speedup vs baseline: 5.9350x; 1.1580x over previous
//
#include <hip/hip_runtime.h>
#include <math.h>

#define BN 4
#define SN 1024
#define EN 512
#define HN 8
#define LN 4
#define DN 64
#define OBSN 128
#define NR (BN*SN)            // 4096 rows
#define NB (NR*EN)            // elements per activation buffer
#define EPSF 1e-6f

typedef __attribute__((ext_vector_type(8))) short short8v;
typedef __attribute__((ext_vector_type(4))) float f32x4;
typedef unsigned short u16;

__device__ __forceinline__ float logk_of(int h){
    const float start = -3.4657359027997265f;   // log(1/32)
    const float step  = -0.3960841031771117f;   // (log(1/512)-log(1/32))/7
    return logf(1.0f - expf(start + step*(float)h));
}
__device__ __forceinline__ float geluf(float x){
    float x3 = x*x*x;
    return 0.5f*x*(1.0f + tanhf(0.7978845608028654f*(x + 0.044715f*x3)));
}
__device__ __forceinline__ float siluf(float x){
    return x / (1.0f + expf(-x));
}
__device__ __forceinline__ u16 f2bf(float x){
    union { float f; unsigned u; } v; v.f = x;
    unsigned r = v.u + 0x7FFFu + ((v.u >> 16) & 1u);
    return (u16)(r >> 16);
}
__device__ __forceinline__ float bf2f(u16 x){
    union { unsigned u; float f; } v; v.u = ((unsigned)x)<<16;
    return v.f;
}
__device__ __forceinline__ void load_lds16(const void* g, void* l){
    __builtin_amdgcn_global_load_lds((const __attribute__((address_space(1))) void*)g,
                                     (__attribute__((address_space(3))) void*)l, 16, 0, 0);
}
// XOR swizzle for 64-row x 128B LDS tiles
__device__ __forceinline__ int swz(int r, int bo){ return r*128 + (bo ^ ((r&7)<<4)); }

// ---------------- segment cumsum (inclusive) ----------------
__global__ void seg_kernel(const int* __restrict__ dones, int* __restrict__ seg){
    __shared__ int sm[SN];
    int b = blockIdx.x, t = threadIdx.x;
    sm[t] = dones[b*SN + t];
    __syncthreads();
    for (int off=1; off<SN; off<<=1){
        int v = (t>=off) ? sm[t-off] : 0;
        __syncthreads();
        sm[t] += v;
        __syncthreads();
    }
    seg[b*SN + t] = sm[t];
}

// ---------------- weight convert+transpose: f32 [K][M] -> bf16 [M][K] ----------------
__global__ void wconv8_kernel(const float* w0, const float* w1, const float* w2,
                              const float* w3, const float* w4, const float* w5,
                              const float* w6, const float* w7,
                              u16* __restrict__ dst){
    __shared__ u16 tile[32][33];
    int z = blockIdx.z;
    int type = z>>2, layer = z&3;
    const float* srcs[8] = {w0,w1,w2,w3,w4,w5,w6,w7};
    const float* s = srcs[type] + (size_t)layer*EN*EN;
    u16* d = dst + ((size_t)type*LN + layer)*EN*EN;
    int k0 = blockIdx.y*32, m0 = blockIdx.x*32;
    int tx = threadIdx.x, ty = threadIdx.y;   // 32, 8
    #pragma unroll
    for (int i=0;i<32;i+=8)
        tile[tx][ty+i] = f2bf(s[(size_t)(k0+ty+i)*EN + m0+tx]);
    __syncthreads();
    #pragma unroll
    for (int i=0;i<32;i+=8)
        d[(size_t)(m0+ty+i)*EN + k0+tx] = tile[ty+i][tx];
}
__global__ void wconv_kernel(const float* __restrict__ src, u16* __restrict__ dst,
                             int K, int M){
    __shared__ u16 tile[32][33];
    int k0 = blockIdx.y*32, m0 = blockIdx.x*32;
    int tx = threadIdx.x, ty = threadIdx.y;
    #pragma unroll
    for (int i=0;i<32;i+=8)
        tile[tx][ty+i] = f2bf(src[(size_t)(k0+ty+i)*M + m0+tx]);
    __syncthreads();
    #pragma unroll
    for (int i=0;i<32;i+=8)
        dst[(size_t)(m0+ty+i)*K + k0+tx] = tile[ty+i][tx];
}

// ---------------- rmsnorm (one wave per row), optional f32 + bf16 outputs ----------------
template<int COLS, bool WF32, bool WBF>
__global__ void rmsnorm_kernel(const float* __restrict__ A,
                               const float* __restrict__ scale,
                               float* __restrict__ Of,
                               u16* __restrict__ Ob){
    constexpr int PER = COLS/64;
    int row  = blockIdx.x*4 + (threadIdx.x>>6);
    int lane = threadIdx.x & 63;
    const float* a = A + (size_t)row*COLS;
    float v[PER];
    float ss = 0.f;
    #pragma unroll
    for (int i=0;i<PER;i++){
        float x = a[lane + i*64];
        v[i] = x; ss += x*x;
    }
    #pragma unroll
    for (int off=32; off>0; off>>=1) ss += __shfl_xor(ss, off, 64);
    float rs = rsqrtf(ss*(1.0f/COLS) + EPSF);
    #pragma unroll
    for (int i=0;i<PER;i++){
        float o = v[i]*rs*scale[lane + i*64];
        if (WF32) Of[(size_t)row*COLS + lane + i*64] = o;
        if (WBF)  Ob[(size_t)row*COLS + lane + i*64] = f2bf(o);
    }
}

// ======== shared MFMA tile helpers (BM=BN=64, BK=64, 256 thr, 4 waves 2x2) ========
__device__ __forceinline__ void stage_tile(const u16* __restrict__ G, size_t rowBase,
                                           int K, int k0, u16* dst, int t){
    #pragma unroll
    for (int i=0;i<2;i++){
        int o = i*4096 + t*16;
        int grow = o>>7, gcolb = o&127;
        load_lds16(G + (rowBase+grow)*K + k0 + (gcolb>>1), (char*)dst + o);
    }
}
__device__ __forceinline__ void mma_tile(const u16* As, const u16* Bs, f32x4 acc[2][2],
                                         int wr, int wc, int lane){
    #pragma unroll
    for (int kk=0; kk<64; kk+=32){
        int kb = kk + (lane>>4)*8;
        short8v a[2], b[2];
        #pragma unroll
        for (int m=0;m<2;m++)
            a[m] = *(const short8v*)((const char*)As + (wr*32+m*16+(lane&15))*128 + kb*2);
        #pragma unroll
        for (int n=0;n<2;n++)
            b[n] = *(const short8v*)((const char*)Bs + (wc*32+n*16+(lane&15))*128 + kb*2);
        #pragma unroll
        for (int m=0;m<2;m++)
            #pragma unroll
            for (int n=0;n<2;n++)
                acc[m][n] = __builtin_amdgcn_mfma_f32_16x16x32_bf16(a[m], b[n], acc[m][n], 0,0,0);
    }
}
#define ZERO_ACC(acc) { _Pragma("unroll") for (int m=0;m<2;m++) _Pragma("unroll") for (int n=0;n<2;n++){ acc[m][n][0]=0.f;acc[m][n][1]=0.f;acc[m][n][2]=0.f;acc[m][n][3]=0.f; } }

// ---------------- fused QKVG GEMM (2-phase pipelined) ----------------
__global__ __launch_bounds__(256) void gemm_qkvg(
    const u16* __restrict__ A,
    const u16* __restrict__ WQ, const u16* __restrict__ WK,
    const u16* __restrict__ WV, const u16* __restrict__ WG,
    u16* __restrict__ Qbb, u16* __restrict__ Kbb,
    u16* __restrict__ VtT, u16* __restrict__ KtT, float* __restrict__ Gb)
{
    __shared__ u16 As[2][64*64];
    __shared__ u16 Bs[2][4][64*64];
    int t = threadIdx.x;
    int row0 = blockIdx.y*64, col0 = blockIdx.x*64;
    int w = t>>6, lane = t&63;
    int wr = w>>1, wc = w&1;
    f32x4 accQ[2][2], accK[2][2], accV[2][2], accG[2][2];
    ZERO_ACC(accQ); ZERO_ACC(accK); ZERO_ACC(accV); ZERO_ACC(accG);
    const u16* Ws[4] = {WQ, WK, WV, WG};

    stage_tile(A, (size_t)row0, EN, 0, As[0], t);
    #pragma unroll
    for (int wt=0; wt<4; wt++) stage_tile(Ws[wt], (size_t)col0, EN, 0, Bs[0][wt], t);
    __syncthreads();
    for (int ti=0; ti<EN/64; ++ti){
        int cur = ti&1;
        if (ti+1 < EN/64){
            stage_tile(A, (size_t)row0, EN, (ti+1)*64, As[cur^1], t);
            #pragma unroll
            for (int wt=0; wt<4; wt++)
                stage_tile(Ws[wt], (size_t)col0, EN, (ti+1)*64, Bs[cur^1][wt], t);
        }
        mma_tile(As[cur], Bs[cur][0], accQ, wr, wc, lane);
        mma_tile(As[cur], Bs[cur][1], accK, wr, wc, lane);
        mma_tile(As[cur], Bs[cur][2], accV, wr, wc, lane);
        mma_tile(As[cur], Bs[cur][3], accG, wr, wc, lane);
        __syncthreads();
    }
    #pragma unroll
    for (int m=0;m<2;m++){
        #pragma unroll
        for (int n=0;n<2;n++){
            int col = col0 + wc*32 + n*16 + (lane&15);
            int rbase = row0 + wr*32 + m*16 + (lane>>4)*4;
            ushort4 pkV, pkK;
            #pragma unroll
            for (int j=0;j<4;j++){
                size_t idx = (size_t)(rbase+j)*EN + col;
                Qbb[idx] = f2bf(accQ[m][n][j]);
                float kx = accK[m][n][j]*0.125f;
                Kbb[idx] = f2bf(kx);
                ((u16*)&pkK)[j] = f2bf(kx);
                ((u16*)&pkV)[j] = f2bf(accV[m][n][j]);
                Gb[idx] = siluf(accG[m][n][j]);
            }
            int bb = rbase>>10;
            int s0 = rbase&1023;
            *(ushort4*)(VtT + ((size_t)bb*EN + col)*SN + s0) = pkV;
            *(ushort4*)(KtT + ((size_t)bb*EN + col)*SN + s0) = pkK;
        }
    }
}

// ---------------- fused swiglu pair (2-phase): Out = bf16(silu(A@Wg)*(A@Wl)) ----------------
__global__ __launch_bounds__(256) void gemm_swpair(
    const u16* __restrict__ A,
    const u16* __restrict__ WGt, const u16* __restrict__ WLt,
    u16* __restrict__ Out)
{
    __shared__ u16 As[2][64*64];
    __shared__ u16 Bg[2][64*64];
    __shared__ u16 Bl[2][64*64];
    int t = threadIdx.x;
    int row0 = blockIdx.y*64, col0 = blockIdx.x*64;
    int w = t>>6, lane = t&63;
    int wr = w>>1, wc = w&1;
    f32x4 accG[2][2], accL[2][2];
    ZERO_ACC(accG); ZERO_ACC(accL);
    stage_tile(A, (size_t)row0, EN, 0, As[0], t);
    stage_tile(WGt, (size_t)col0, EN, 0, Bg[0], t);
    stage_tile(WLt, (size_t)col0, EN, 0, Bl[0], t);
    __syncthreads();
    for (int ti=0; ti<EN/64; ++ti){
        int cur = ti&1;
        if (ti+1 < EN/64){
            stage_tile(A, (size_t)row0, EN, (ti+1)*64, As[cur^1], t);
            stage_tile(WGt, (size_t)col0, EN, (ti+1)*64, Bg[cur^1], t);
            stage_tile(WLt, (size_t)col0, EN, (ti+1)*64, Bl[cur^1], t);
        }
        mma_tile(As[cur], Bg[cur], accG, wr, wc, lane);
        mma_tile(As[cur], Bl[cur], accL, wr, wc, lane);
        __syncthreads();
    }
    #pragma unroll
    for (int m=0;m<2;m++){
        #pragma unroll
        for (int n=0;n<2;n++){
            int col = col0 + wc*32 + n*16 + (lane&15);
            int rbase = row0 + wr*32 + m*16 + (lane>>4)*4;
            #pragma unroll
            for (int j=0;j<4;j++){
                float x = siluf(accG[m][n][j]) * accL[m][n][j];
                Out[(size_t)(rbase+j)*EN + col] = f2bf(x);
            }
        }
    }
}

// ---------------- plain bf16 GEMM (2-phase) ----------------
template<int ACT, bool BIASF, bool RESF, int OUTM>
__global__ __launch_bounds__(256) void gemm_bf16(
    const u16* __restrict__ A, const u16* __restrict__ Wt,
    const float* __restrict__ bias, const float* __restrict__ res,
    float* __restrict__ C, u16* __restrict__ Ob, int K, float scale)
{
    __shared__ u16 As[2][64*64];
    __shared__ u16 Bs[2][64*64];
    int t = threadIdx.x;
    int row0 = blockIdx.y*64, col0 = blockIdx.x*64;
    int w = t>>6, lane = t&63;
    int wr = w>>1, wc = w&1;
    f32x4 acc[2][2];
    ZERO_ACC(acc);
    int nt = K/64;
    stage_tile(A, (size_t)row0, K, 0, As[0], t);
    stage_tile(Wt, (size_t)col0, K, 0, Bs[0], t);
    __syncthreads();
    for (int ti=0; ti<nt; ++ti){
        int cur = ti&1;
        if (ti+1 < nt){
            stage_tile(A, (size_t)row0, K, (ti+1)*64, As[cur^1], t);
            stage_tile(Wt, (size_t)col0, K, (ti+1)*64, Bs[cur^1], t);
        }
        mma_tile(As[cur], Bs[cur], acc, wr, wc, lane);
        __syncthreads();
    }
    #pragma unroll
    for (int m=0;m<2;m++){
        #pragma unroll
        for (int n=0;n<2;n++){
            int col = col0 + wc*32 + n*16 + (lane&15);
            int rbase = row0 + wr*32 + m*16 + (lane>>4)*4;
            #pragma unroll
            for (int j=0;j<4;j++){
                float x = acc[m][n][j]*scale;
                if (BIASF) x += bias[col];
                if (ACT==1) x = siluf(x);
                if (ACT==2) x = geluf(x);
                if (RESF) x += res[(size_t)(rbase+j)*512 + col];
                if (OUTM&1) C[(size_t)(rbase+j)*512 + col] = x;
                if (OUTM&2) Ob[(size_t)(rbase+j)*512 + col] = f2bf(x);
            }
        }
    }
}

// ---------------- MFMA retention + fused groupnorm + gate-mul + fused h_new ----------------
// grid (17, B*H): blockIdx.x==0 -> h_new role; else q-tile = 16-blockIdx.x (heavy first).
__global__ __launch_bounds__(256) void retention_mfma(
    const u16* __restrict__ Qbb, const u16* __restrict__ Kbb,
    const u16* __restrict__ VtT, const u16* __restrict__ KtT,
    const float* __restrict__ hstate, const int* __restrict__ tsid, const int* __restrict__ seg,
    const float* __restrict__ gns, const float* __restrict__ gnb,
    const float* __restrict__ Gb, u16* __restrict__ Out,
    float* __restrict__ Hout, int layer)
{
    int bh = blockIdx.y; int b = bh>>3; int h = bh&7;
    int t = threadIdx.x, lane = t&63, w = t>>6;
    __shared__ u16 Qs[64*64];
    __shared__ u16 Ks[64*64];
    __shared__ u16 Vts[64*64];
    __shared__ u16 Ps[64*64];
    __shared__ float tsq_s[64], eq_s[64], xi_s[64];
    __shared__ int   segq_s[64];
    __shared__ float tsm_s[64], em_s[64];
    __shared__ int   segm_s[64];
    float lk = logk_of(h);

    if (blockIdx.x == 0){
        // ---- h_new role: Hout = h0*hd + sum_m eta[m] k[m]^T v[m]  (MFMA) ----
        float tmax = (float)tsid[b*SN + SN-1];
        int segl = seg[b*SN + SN-1];
        float* eta = (float*)Qs;          // 1024 f32 in Qs region
        #pragma unroll
        for (int i=0;i<4;i++){
            int m = t + i*256;
            float tsm = (float)tsid[b*SN+m];
            eta[m] = (seg[b*SN+m]==segl) ? expf((tmax - tsm)*lk) : 0.f;
        }
        f32x4 eacc[4];
        #pragma unroll
        for (int en=0;en<4;en++){ eacc[en][0]=0.f; eacc[en][1]=0.f; eacc[en][2]=0.f; eacc[en][3]=0.f; }
        for (int mt=0; mt<16; ++mt){
            int m0 = mt*64;
            __syncthreads();
            #pragma unroll
            for (int i=0;i<2;i++){
                int c = t + i*256; int r = c>>3, cb = (c&7)*16;
                int mb = m0 + (cb>>1);
                size_t g = ((size_t)(b*EN) + h*DN + r)*SN + mb;
                short8v kt = *(const short8v*)(KtT + g);
                short8v vt = *(const short8v*)(VtT + g);
                short8v ks;
                #pragma unroll
                for (int j=0;j<8;j++) ks[j] = (short)f2bf(bf2f((u16)kt[j]) * eta[mb+j]);
                *(short8v*)((char*)Ks  + swz(r,cb)) = ks;
                *(short8v*)((char*)Vts + swz(r,cb)) = vt;
            }
            __syncthreads();
            short8v a0 = *(short8v*)((char*)Ks + swz(w*16+(lane&15), (lane>>4)*16));
            short8v a1 = *(short8v*)((char*)Ks + swz(w*16+(lane&15), 64+(lane>>4)*16));
            __builtin_amdgcn_s_setprio(1);
            #pragma unroll
            for (int en=0;en<4;en++){
                short8v b0 = *(short8v*)((char*)Vts + swz(en*16+(lane&15), (lane>>4)*16));
                short8v b1 = *(short8v*)((char*)Vts + swz(en*16+(lane&15), 64+(lane>>4)*16));
                eacc[en] = __builtin_amdgcn_mfma_f32_16x16x32_bf16(a0, b0, eacc[en], 0,0,0);
                eacc[en] = __builtin_amdgcn_mfma_f32_16x16x32_bf16(a1, b1, eacc[en], 0,0,0);
            }
            __builtin_amdgcn_s_setprio(0);
        }
        float hd = (segl==0) ? expf((tmax+1.0f)*lk) : 0.f;
        const float* h0 = hstate + ((size_t)bh*LN + layer)*4096;
        float* ho = Hout + ((size_t)bh*LN + layer)*4096;
        #pragma unroll
        for (int en=0;en<4;en++){
            int e = en*16 + (lane&15);
            #pragma unroll
            for (int j=0;j<4;j++){
                int d = w*16 + (lane>>4)*4 + j;
                ho[d*64 + e] = h0[d*64 + e]*hd + eacc[en][j];
            }
        }
        return;
    }

    // ---- retention role ----
    int tile = 16 - (int)blockIdx.x;   // 15..0, heavy first
    int n0 = tile*64;

    #pragma unroll
    for (int i=0;i<2;i++){
        int c = t + i*256; int r = c>>3, cb = (c&7)*16;
        short8v qv = *(const short8v*)(Qbb + (size_t)(b*SN + n0 + r)*EN + h*DN + (cb>>1));
        *(short8v*)((char*)Qs + swz(r,cb)) = qv;
    }
    const float* h0 = hstate + ((size_t)bh*LN + layer)*4096;
    #pragma unroll
    for (int i=0;i<4;i++){
        int idx = t + i*256; int d = idx>>4, e0 = (idx&15)*4;
        float4 hv = *(const float4*)(h0 + d*64 + e0);
        *(u16*)((char*)Ps + swz(e0+0, 2*d)) = f2bf(hv.x);
        *(u16*)((char*)Ps + swz(e0+1, 2*d)) = f2bf(hv.y);
        *(u16*)((char*)Ps + swz(e0+2, 2*d)) = f2bf(hv.z);
        *(u16*)((char*)Ps + swz(e0+3, 2*d)) = f2bf(hv.w);
    }
    if (t<64){
        float tq = (float)tsid[b*SN+n0+t];
        int sg = seg[b*SN+n0+t];
        tsq_s[t]=tq; segq_s[t]=sg;
        eq_s[t]=expf(tq*lk);
        xi_s[t]=(sg==0)?expf((tq+1.f)*lk):0.f;
    }
    // prefetch m-tile 0 K/V into registers (T14)
    short8v kr0, kr1, vr0, vr1;
    {
        int c0 = t, c1 = t+256;
        int r0=c0>>3, cb0=(c0&7)*16, r1=c1>>3, cb1=(c1&7)*16;
        kr0 = *(const short8v*)(Kbb + (size_t)(b*SN+r0)*EN + h*DN + (cb0>>1));
        kr1 = *(const short8v*)(Kbb + (size_t)(b*SN+r1)*EN + h*DN + (cb1>>1));
        vr0 = *(const short8v*)(VtT + ((size_t)(b*EN)+h*DN+r0)*SN + (cb0>>1));
        vr1 = *(const short8v*)(VtT + ((size_t)(b*EN)+h*DN+r1)*SN + (cb1>>1));
    }
    __syncthreads();

    int qlj = w*16 + ((lane>>4)<<2);
    float tsq_r[4], eq_r[4], xi_r[4]; int sgq_r[4];
    #pragma unroll
    for (int j=0;j<4;j++){
        tsq_r[j]=tsq_s[qlj+j]; eq_r[j]=eq_s[qlj+j];
        xi_r[j]=xi_s[qlj+j];  sgq_r[j]=segq_s[qlj+j];
    }
    short8v aq0 = *(short8v*)((char*)Qs + swz(w*16+(lane&15), (lane>>4)*16));
    short8v aq1 = *(short8v*)((char*)Qs + swz(w*16+(lane&15), 64 + (lane>>4)*16));

    // cross term: oacc = xi[q] * (Q @ h0)
    f32x4 oacc[4];
    {
        f32x4 cacc[4];
        #pragma unroll
        for (int en=0;en<4;en++){ cacc[en][0]=0.f; cacc[en][1]=0.f; cacc[en][2]=0.f; cacc[en][3]=0.f; }
        #pragma unroll
        for (int en=0;en<4;en++){
            short8v b0 = *(short8v*)((char*)Ps + swz(en*16+(lane&15), (lane>>4)*16));
            short8v b1 = *(short8v*)((char*)Ps + swz(en*16+(lane&15), 64+(lane>>4)*16));
            cacc[en] = __builtin_amdgcn_mfma_f32_16x16x32_bf16(aq0, b0, cacc[en], 0,0,0);
            cacc[en] = __builtin_amdgcn_mfma_f32_16x16x32_bf16(aq1, b1, cacc[en], 0,0,0);
        }
        #pragma unroll
        for (int en=0;en<4;en++)
            #pragma unroll
            for (int j=0;j<4;j++) oacc[en][j] = cacc[en][j]*xi_r[j];
    }

    for (int mt=0; mt<=tile; ++mt){
        int m0 = mt*64;
        __syncthreads();   // previous readers of Ks/Vts (and Hs/Ps cross-term) done
        {   // write prefetched regs -> LDS (swizzled)
            int c0 = t, c1 = t+256;
            int r0=c0>>3, cb0=(c0&7)*16, r1=c1>>3, cb1=(c1&7)*16;
            *(short8v*)((char*)Ks  + swz(r0,cb0)) = kr0;
            *(short8v*)((char*)Ks  + swz(r1,cb1)) = kr1;
            *(short8v*)((char*)Vts + swz(r0,cb0)) = vr0;
            *(short8v*)((char*)Vts + swz(r1,cb1)) = vr1;
        }
        if (t<64){
            float tm = (float)tsid[b*SN+m0+t];
            tsm_s[t]=tm; segm_s[t]=seg[b*SN+m0+t]; em_s[t]=expf(-tm*lk);
        }
        if (mt < tile){   // prefetch next m-tile (flies under the MFMA phase)
            int m1 = m0 + 64;
            int c0 = t, c1 = t+256;
            int r0=c0>>3, cb0=(c0&7)*16, r1=c1>>3, cb1=(c1&7)*16;
            kr0 = *(const short8v*)(Kbb + (size_t)(b*SN+m1+r0)*EN + h*DN + (cb0>>1));
            kr1 = *(const short8v*)(Kbb + (size_t)(b*SN+m1+r1)*EN + h*DN + (cb1>>1));
            vr0 = *(const short8v*)(VtT + ((size_t)(b*EN)+h*DN+r0)*SN + m1 + (cb0>>1));
            vr1 = *(const short8v*)(VtT + ((size_t)(b*EN)+h*DN+r1)*SN + m1 + (cb1>>1));
        }
        __syncthreads();
        f32x4 sacc[4];
        #pragma unroll
        for (int mn=0;mn<4;mn++){ sacc[mn][0]=0.f; sacc[mn][1]=0.f; sacc[mn][2]=0.f; sacc[mn][3]=0.f; }
        __builtin_amdgcn_s_setprio(1);
        #pragma unroll
        for (int mn=0;mn<4;mn++){
            short8v b0 = *(short8v*)((char*)Ks + swz(mn*16+(lane&15), (lane>>4)*16));
            short8v b1 = *(short8v*)((char*)Ks + swz(mn*16+(lane&15), 64+(lane>>4)*16));
            sacc[mn] = __builtin_amdgcn_mfma_f32_16x16x32_bf16(aq0, b0, sacc[mn], 0,0,0);
            sacc[mn] = __builtin_amdgcn_mfma_f32_16x16x32_bf16(aq1, b1, sacc[mn], 0,0,0);
        }
        __builtin_amdgcn_s_setprio(0);
        #pragma unroll
        for (int mn=0;mn<4;mn++){
            int m = mn*16 + (lane&15);
            float tm = tsm_s[m]; float em = em_s[m]; int sgm = segm_s[m];
            #pragma unroll
            for (int j=0;j<4;j++){
                float p = (tsq_r[j]>=tm && sgq_r[j]==sgm) ? sacc[mn][j]*eq_r[j]*em : 0.f;
                *(u16*)((char*)Ps + swz(qlj+j, 2*m)) = f2bf(p);
            }
        }
        short8v ap0 = *(short8v*)((char*)Ps + swz(w*16+(lane&15), (lane>>4)*16));
        short8v ap1 = *(short8v*)((char*)Ps + swz(w*16+(lane&15), 64+(lane>>4)*16));
        __builtin_amdgcn_s_setprio(1);
        #pragma unroll
        for (int dn=0;dn<4;dn++){
            short8v b0 = *(short8v*)((char*)Vts + swz(dn*16+(lane&15), (lane>>4)*16));
            short8v b1 = *(short8v*)((char*)Vts + swz(dn*16+(lane&15), 64+(lane>>4)*16));
            oacc[dn] = __builtin_amdgcn_mfma_f32_16x16x32_bf16(ap0, b0, oacc[dn], 0,0,0);
            oacc[dn] = __builtin_amdgcn_mfma_f32_16x16x32_bf16(ap1, b1, oacc[dn], 0,0,0);
        }
        __builtin_amdgcn_s_setprio(0);
    }

    // fused groupnorm + gate multiply
    float mu[4], rs[4];
    #pragma unroll
    for (int j=0;j<4;j++){
        float s = oacc[0][j]+oacc[1][j]+oacc[2][j]+oacc[3][j];
        #pragma unroll
        for (int off=1; off<16; off<<=1) s += __shfl_xor(s, off, 64);
        mu[j] = s*(1.0f/64.0f);
        float d0=oacc[0][j]-mu[j], d1=oacc[1][j]-mu[j], d2=oacc[2][j]-mu[j], d3=oacc[3][j]-mu[j];
        float q2 = d0*d0+d1*d1+d2*d2+d3*d3;
        #pragma unroll
        for (int off=1; off<16; off<<=1) q2 += __shfl_xor(q2, off, 64);
        rs[j] = rsqrtf(q2*(1.0f/64.0f) + EPSF);
    }
    #pragma unroll
    for (int dn=0;dn<4;dn++){
        int e = h*DN + dn*16 + (lane&15);
        float gs = gns[e], gb = gnb[e];
        #pragma unroll
        for (int j=0;j<4;j++){
            size_t row = (size_t)(b*SN + n0 + qlj + j);
            float y = (oacc[dn][j]-mu[j])*rs[j]*gs + gb;
            Out[row*EN + e] = f2bf(y * Gb[row*EN + e]);
        }
    }
}

// ---------------- v_loc = ZN @ w2 + b2 (M=1) ----------------
__global__ void vloc_kernel(const float* __restrict__ ZN, const float* __restrict__ w2,
                            const float* __restrict__ b2, float* __restrict__ out){
    int row  = blockIdx.x*4 + (threadIdx.x>>6);
    int lane = threadIdx.x & 63;
    const float* z = ZN + (size_t)row*EN;
    float s = 0.f;
    #pragma unroll
    for (int i=0;i<8;i++) s += z[lane + i*64]*w2[lane + i*64];
    #pragma unroll
    for (int off=32; off>0; off>>=1) s += __shfl_xor(s, off, 64);
    if (lane==0) out[row] = s + b2[0];
}

// ---------------- host ----------------
static inline void launch_gemm(const u16* A, const u16* Wt, const float* bias,
                               const float* res, float* C, u16* Ob,
                               int K, float scale, int act, int outm, hipStream_t s){
    dim3 g(8, 64), b(256,1,1);
    if (bias)                    gemm_bf16<2,true ,false,1><<<g,b,0,s>>>(A,Wt,bias,res,C,Ob,K,scale);
    else if (res && outm==3)     gemm_bf16<0,false,true ,3><<<g,b,0,s>>>(A,Wt,bias,res,C,Ob,K,scale);
    else if (res)                gemm_bf16<0,false,true ,1><<<g,b,0,s>>>(A,Wt,bias,res,C,Ob,K,scale);
    else if (act==2)             gemm_bf16<2,false,false,1><<<g,b,0,s>>>(A,Wt,bias,res,C,Ob,K,scale);
    else                         gemm_bf16<0,false,false,1><<<g,b,0,s>>>(A,Wt,bias,res,C,Ob,K,scale);
}

extern "C" void kernel_launch(void* const* d_in, const int* in_sizes, int n_in,
                              void* d_out, int out_size, void* d_ws, size_t ws_size,
                              hipStream_t stream){
    const float* obs       = (const float*)d_in[0];
    const float* hstate    = (const float*)d_in[1];
    const int*   dones     = (const int*)  d_in[2];
    const int*   tsid      = (const int*)  d_in[3];
    const float* ln_enc    = (const float*)d_in[4];
    const float* w_enc     = (const float*)d_in[5];
    const float* ln_shared = (const float*)d_in[6];
    const float* wq        = (const float*)d_in[7];
    const float* wk        = (const float*)d_in[8];
    const float* wv        = (const float*)d_in[9];
    const float* wg        = (const float*)d_in[10];
    const float* wo        = (const float*)d_in[11];
    const float* gns       = (const float*)d_in[12];
    const float* gnb       = (const float*)d_in[13];
    const float* ln1       = (const float*)d_in[14];
    const float* ln2       = (const float*)d_in[15];
    const float* swg       = (const float*)d_in[16];
    const float* swl       = (const float*)d_in[17];
    const float* swo       = (const float*)d_in[18];
    const float* hw1       = (const float*)d_in[19];
    const float* hb1       = (const float*)d_in[20];
    const float* hln       = (const float*)d_in[21];
    const float* hw2       = (const float*)d_in[22];
    const float* hb2       = (const float*)d_in[23];

    float* out_v = (float*)d_out;                 // (B,S,1)
    float* out_x = out_v + NR;                    // (B,S,E)
    float* out_h = out_x + (size_t)NR*EN;         // (B,H,L,D,D)

    float* ws    = (float*)d_ws;
    float* XIN   = ws + 0*(size_t)NB;
    float* Qb    = ws + 1*(size_t)NB;   // f32 temp; VtT+KtT alias it
    float* Kb    = ws + 2*(size_t)NB;
    float* Vb    = ws + 3*(size_t)NB;   // (spare)
    float* Gb    = ws + 4*(size_t)NB;
    float* Yb    = ws + 5*(size_t)NB;
    int*   seg   = (int*)(ws + 6*(size_t)NB);
    u16* wtb  = (u16*)(seg + NR);
    const size_t WEm = (size_t)EN*EN;
    u16* wqT   = wtb;                 // type 0
    u16* wkT   = wqT + 4*WEm;         // type 1
    u16* wvT   = wkT + 4*WEm;         // type 2
    u16* wgT   = wvT + 4*WEm;         // type 3
    u16* woT   = wgT + 4*WEm;         // type 4
    u16* sgT   = woT + 4*WEm;         // type 5
    u16* slT   = sgT + 4*WEm;         // type 6
    u16* soT   = slT + 4*WEm;         // type 7
    u16* wencT = soT + 4*WEm;
    u16* w1T   = wencT + (size_t)EN*OBSN;
    u16* S1b   = w1T + WEm;
    u16* S2b   = S1b + (size_t)NB;
    u16* encb  = S2b + (size_t)NB;
    u16* Qbb   = encb + (size_t)NR*OBSN;
    u16* Kbb   = Qbb + (size_t)NB;
    u16* VtT   = (u16*)Qb;             // bf16 V^T [B][512][S]  (4 MB)
    u16* KtT   = VtT + (size_t)NB;     // bf16 K^T [B][512][S]  (4 MB) — both inside Qb slot

    seg_kernel<<<BN, SN, 0, stream>>>(dones, seg);

    {
        dim3 tb(32,8,1);
        wconv8_kernel<<<dim3(16,16,32), tb, 0, stream>>>(wq,wk,wv,wg,wo,swg,swl,swo, wtb);
        wconv_kernel<<<dim3(16,4,1),  tb, 0, stream>>>(w_enc, wencT, OBSN, EN);
        wconv_kernel<<<dim3(16,16,1), tb, 0, stream>>>(hw1,   w1T,   EN, EN);
    }

    // encoder
    rmsnorm_kernel<OBSN,false,true><<<NR/4, 256, 0, stream>>>(obs, ln_enc, nullptr, encb);
    launch_gemm(encb, wencT, nullptr, nullptr, out_x, nullptr, OBSN, 1.f, 2, 1, stream);

    for (int l=0; l<LN; ++l){
        rmsnorm_kernel<EN,true,true><<<NR/4, 256, 0, stream>>>(out_x, ln_shared, XIN, S1b);
        gemm_qkvg<<<dim3(8,64), 256, 0, stream>>>(S1b,
            wqT + l*WEm, wkT + l*WEm, wvT + l*WEm, wgT + l*WEm,
            Qbb, Kbb, VtT, KtT, Gb);
        retention_mfma<<<dim3(17, BN*HN), 256, 0, stream>>>(
            Qbb, Kbb, VtT, KtT, hstate, tsid, seg, gns + l*EN, gnb + l*EN,
            Gb, S2b, out_h, l);
        launch_gemm(S2b, woT + l*WEm, nullptr, XIN, Qb, nullptr, EN, 1.f, 0, 1, stream); // Qb = ret@wo + xin
        rmsnorm_kernel<EN,true,true><<<NR/4, 256, 0, stream>>>(Qb, ln1 + l*EN, Kb, S1b); // x1
        gemm_swpair<<<dim3(8,64), 256, 0, stream>>>(S1b, sgT + l*WEm, slT + l*WEm, S2b);
        launch_gemm(S2b, soT + l*WEm, nullptr, Kb, Qb, nullptr, EN, 1.f, 0, 1, stream);  // Qb = t@swo + x1
        if (l == LN-1)
            rmsnorm_kernel<EN,true,true ><<<NR/4, 256, 0, stream>>>(Qb, ln2 + l*EN, out_x, S1b);
        else
            rmsnorm_kernel<EN,true,false><<<NR/4, 256, 0, stream>>>(Qb, ln2 + l*EN, out_x, nullptr);
    }

    // head
    launch_gemm(S1b, w1T, hb1, nullptr, Yb, nullptr, EN, 1.f, 2, 1, stream);
    rmsnorm_kernel<EN,true,false><<<NR/4, 256, 0, stream>>>(Yb, hln, XIN, nullptr);
    vloc_kernel<<<NR/4, 256, 0, stream>>>(XIN, hw2, hb2, out_v);
}